// Round 3
// baseline (1986.390 us; speedup 1.0000x reference)
//
#include <hip/hip_runtime.h>
#include <hip/hip_bf16.h>

// CGCNN forward, decomposition form:
//   gated[n,m,:] = ys[n,:] + yn[nbr[n,m],:] + bond[n,m,:]@W3
// with ys = x@W1 + b, yn = x@W2  (W1=Wf[0:64], W2=Wf[64:128], W3=Wf[128:169]).
// Runtime dtype detection: float inputs may be fp32 or bf16; a detect kernel
// votes on bit patterns, weights are converted to canonical fp32 scratch,
// bulk tensors (atom_fea, nbr_fea) use flag-branched loads, output write is
// flag-branched. BN is training-mode: stats pass, then activation pass.

#define NATOM 60000
#define MNBR  12
#define F0D   92
#define FBD   41
#define FD    64
#define F2D   128
#define NCRY  2000
#define HD    128

// ws layout (floats)
#define OFF_X      0ull
#define OFF_SUMMED 3840000ull
#define OFF_YS     7680000ull      // crys/cnt overlay here after conv layers
#define OFF_CRYS   7680000ull
#define OFF_CNT    7808000ull
#define OFF_YN     15360000ull
#define OFF_STATS  23040000ull     // sum1[128] sq1[128] sum2[64] sq2[64]
#define OFF_WCONV  23040384ull     // 80833 floats of converted weights
#define OFF_FLAG   23121218ull
#define WS_NEED_BYTES ((23121220ull) * 4ull)

// offsets inside wconv
#define W_EMB_O  0
#define B_EMB_O  5888
#define W_FULL_O 5952
#define B_FULL_O 70848
#define G1_O     71232
#define BE1_O    71616
#define G2_O     72000
#define BE2_O    72192
#define W_FC_O   72384
#define B_FC_O   80576
#define W_OUT_O  80704
#define B_OUT_O  80832

typedef unsigned short u16;

__device__ __forceinline__ float bf2f(u16 u){
  union { unsigned int i; float f; } v; v.i = ((unsigned int)u) << 16; return v.f;
}
__device__ __forceinline__ u16 f2bf(float f){
  union { float f; unsigned int i; } v; v.f = f;
  unsigned int x = v.i;
  return (u16)((x + 0x7FFFu + ((x >> 16) & 1u)) >> 16);
}
__device__ __forceinline__ float softplusf_(float x){
  return fmaxf(x, 0.f) + log1pf(expf(-fabsf(x)));
}
__device__ __forceinline__ float sigmoidf_(float x){
  return 1.f / (1.f + expf(-x));
}

// Decide dtype of float inputs. Even-indexed u16s of an fp32 N(0,1) array are
// low mantissa halves (random exponent when read as bf16 -> mostly insane);
// of a bf16 array they are genuine N(0,1) samples (sane). Majority vote.
__global__ __launch_bounds__(64) void detect_kernel(
    const u16* __restrict__ data, int* __restrict__ flag){
  int tid = threadIdx.x;
  float v = bf2f(data[tid * 2]);
  float av = fabsf(v);
  bool sane = (av > 1e-6f) && (av < 100.f);   // NaN/inf fail
  unsigned long long m = __ballot(sane);
  if (tid == 0) *flag = (__popcll(m) >= 32) ? 1 : 0;   // 1 = bf16
}

__global__ __launch_bounds__(256) void cvt_kernel(
    const void* __restrict__ src, float* __restrict__ dst, int n,
    const int* __restrict__ flag){
  int i = blockIdx.x * 256 + threadIdx.x;
  if (i >= n) return;
  if (*flag) dst[i] = bf2f(((const u16*)src)[i]);
  else       dst[i] = ((const float*)src)[i];
}

// x = atom_fea @ W_emb + b_emb   (60000x92 @ 92x64)
__global__ __launch_bounds__(256) void embed_kernel(
    const void* __restrict__ atom_fea, const float* __restrict__ W_emb,
    const float* __restrict__ b_emb, float* __restrict__ x,
    const int* __restrict__ flag){
  int tid = threadIdx.x;
  int n = blockIdx.x * 4 + (tid >> 6);
  int f = tid & 63;
  float acc = b_emb[f];
  if (*flag){
    const u16* arow = (const u16*)atom_fea + n * F0D;
    for (int k = 0; k < F0D; k++)
      acc = fmaf(bf2f(arow[k]), W_emb[k * FD + f], acc);
  } else {
    const float* arow = (const float*)atom_fea + n * F0D;
    for (int k = 0; k < F0D; k++)
      acc = fmaf(arow[k], W_emb[k * FD + f], acc);
  }
  x[n * FD + f] = acc;
}

// ys = x@W1 + b ; yn = x@W2.  4 waves: (ys|yn) x (cols 0-63|64-127).
__global__ __launch_bounds__(256) void dual_gemm(
    const float* __restrict__ x, const float* __restrict__ Wf,
    const float* __restrict__ bfull, float* __restrict__ ys, float* __restrict__ yn){
  __shared__ float x_s[32 * 64];
  int tid = threadIdx.x;
  int wv = tid >> 6, j = tid & 63;
  int col = ((wv & 1) << 6) + j;
  int krow0 = (wv >> 1) << 6;
  float w[64];
  #pragma unroll
  for (int k = 0; k < 64; k++) w[k] = Wf[(krow0 + k) * F2D + col];
  float bias = (wv >> 1) ? 0.f : bfull[col];
  float* out = (wv >> 1) ? yn : ys;
  int a0 = blockIdx.x * 32;
  for (int i = tid; i < 512; i += 256)
    ((float4*)x_s)[i] = ((const float4*)(x + a0 * 64))[i];
  __syncthreads();
  for (int a = 0; a < 32; a++){
    float acc = bias;
    const float4* xr = (const float4*)&x_s[a * 64];
    #pragma unroll
    for (int kk = 0; kk < 16; kk++){
      float4 xv = xr[kk];
      acc = fmaf(xv.x, w[4*kk+0], acc);
      acc = fmaf(xv.y, w[4*kk+1], acc);
      acc = fmaf(xv.z, w[4*kk+2], acc);
      acc = fmaf(xv.w, w[4*kk+3], acc);
    }
    out[(a0 + a) * F2D + col] = acc;
  }
}

// Pass 1: BN1 column stats of g = ys[n]+yn[nb]+bond@W3 over all edges.
__global__ __launch_bounds__(256) void stats_kernel(
    const float* __restrict__ ys, const float* __restrict__ yn,
    const void* __restrict__ nbr_fea, const int* __restrict__ nbr_idx,
    const float* __restrict__ Wf, float* __restrict__ sum1, float* __restrict__ sq1,
    const int* __restrict__ flag){
  __shared__ float bond_s[4][MNBR][44];
  __shared__ float sum_s[F2D], sq_s[F2D];
  int tid = threadIdx.x, wv = tid >> 6, j = tid & 63;
  const int isbf = *flag;
  if (tid < F2D){ sum_s[tid] = 0.f; sq_s[tid] = 0.f; }
  float w0[41], w1[41];
  #pragma unroll
  for (int k = 0; k < 41; k++){
    w0[k] = Wf[(128 + k) * F2D + j];
    w1[k] = Wf[(128 + k) * F2D + 64 + j];
  }
  float s0 = 0.f, q0 = 0.f, s1 = 0.f, q1 = 0.f;
  for (int base = blockIdx.x * 4; base < NATOM; base += gridDim.x * 4){
    __syncthreads();
    long long gb = (long long)base * 492;
    for (int idx = tid; idx < 4 * 492; idx += 256){
      float bv = isbf ? bf2f(((const u16*)nbr_fea)[gb + idx])
                      : ((const float*)nbr_fea)[gb + idx];
      int aw = idx / 492, rem = idx - aw * 492;
      int m = rem / 41, k = rem - m * 41;
      bond_s[aw][m][k] = bv;
    }
    __syncthreads();
    int a = base + wv;
    const float* ysr = ys + a * F2D;
    float y0 = ysr[j], y1 = ysr[64 + j];
    #pragma unroll
    for (int m = 0; m < MNBR; m++){
      int nb = nbr_idx[a * MNBR + m];
      const float* ynr = yn + nb * F2D;
      float g0 = y0 + ynr[j];
      float g1 = y1 + ynr[64 + j];
      #pragma unroll
      for (int k = 0; k < 41; k++){
        float b = bond_s[wv][m][k];
        g0 = fmaf(b, w0[k], g0);
        g1 = fmaf(b, w1[k], g1);
      }
      s0 += g0; q0 = fmaf(g0, g0, q0);
      s1 += g1; q1 = fmaf(g1, g1, q1);
    }
  }
  atomicAdd(&sum_s[j], s0);      atomicAdd(&sum_s[64 + j], s1);
  atomicAdd(&sq_s[j],  q0);      atomicAdd(&sq_s[64 + j],  q1);
  __syncthreads();
  if (tid < F2D){ atomicAdd(&sum1[tid], sum_s[tid]); atomicAdd(&sq1[tid], sq_s[tid]); }
}

// Pass 2: recompute g, BN1 affine + sigmoid*softplus, sum over m -> summed;
// accumulate BN2 stats.
__global__ __launch_bounds__(256) void act_kernel(
    const float* __restrict__ ys, const float* __restrict__ yn,
    const void* __restrict__ nbr_fea, const int* __restrict__ nbr_idx,
    const float* __restrict__ Wf, const float* __restrict__ sum1,
    const float* __restrict__ sq1, const float* __restrict__ g1,
    const float* __restrict__ be1, float* __restrict__ summed,
    float* __restrict__ sum2, float* __restrict__ sq2,
    const int* __restrict__ flag){
  __shared__ float bond_s[4][MNBR][44];
  __shared__ float s2_s[FD], q2_s[FD];
  int tid = threadIdx.x, wv = tid >> 6, j = tid & 63;
  const int isbf = *flag;
  if (tid < FD){ s2_s[tid] = 0.f; q2_s[tid] = 0.f; }
  float w0[41], w1[41];
  #pragma unroll
  for (int k = 0; k < 41; k++){
    w0[k] = Wf[(128 + k) * F2D + j];
    w1[k] = Wf[(128 + k) * F2D + 64 + j];
  }
  const float invR = 1.f / (float)(NATOM * MNBR);
  float m0 = sum1[j] * invR;
  float v0 = fmaxf(sq1[j] * invR - m0 * m0, 0.f);
  float A0 = g1[j] * rsqrtf(v0 + 1e-5f);
  float B0 = be1[j] - m0 * A0;
  float m1 = sum1[64 + j] * invR;
  float v1 = fmaxf(sq1[64 + j] * invR - m1 * m1, 0.f);
  float A1 = g1[64 + j] * rsqrtf(v1 + 1e-5f);
  float B1 = be1[64 + j] - m1 * A1;
  float s2 = 0.f, q2 = 0.f;
  for (int base = blockIdx.x * 4; base < NATOM; base += gridDim.x * 4){
    __syncthreads();
    long long gb = (long long)base * 492;
    for (int idx = tid; idx < 4 * 492; idx += 256){
      float bv = isbf ? bf2f(((const u16*)nbr_fea)[gb + idx])
                      : ((const float*)nbr_fea)[gb + idx];
      int aw = idx / 492, rem = idx - aw * 492;
      int m = rem / 41, k = rem - m * 41;
      bond_s[aw][m][k] = bv;
    }
    __syncthreads();
    int a = base + wv;
    const float* ysr = ys + a * F2D;
    float y0 = ysr[j], y1 = ysr[64 + j];
    float p = 0.f;
    #pragma unroll
    for (int m = 0; m < MNBR; m++){
      int nb = nbr_idx[a * MNBR + m];
      const float* ynr = yn + nb * F2D;
      float g0 = y0 + ynr[j];
      float g1v = y1 + ynr[64 + j];
      #pragma unroll
      for (int k = 0; k < 41; k++){
        float b = bond_s[wv][m][k];
        g0  = fmaf(b, w0[k], g0);
        g1v = fmaf(b, w1[k], g1v);
      }
      float u = fmaf(g0, A0, B0);
      float v = fmaf(g1v, A1, B1);
      p = fmaf(sigmoidf_(u), softplusf_(v), p);
    }
    summed[a * FD + j] = p;
    s2 += p; q2 = fmaf(p, p, q2);
  }
  atomicAdd(&s2_s[j], s2);
  atomicAdd(&q2_s[j], q2);
  __syncthreads();
  if (tid < FD){ atomicAdd(&sum2[tid], s2_s[tid]); atomicAdd(&sq2[tid], q2_s[tid]); }
}

// x = softplus(x + bn2(summed))
__global__ __launch_bounds__(256) void update_x_kernel(
    float* __restrict__ x, const float* __restrict__ summed,
    const float* __restrict__ sum2, const float* __restrict__ sq2,
    const float* __restrict__ g2, const float* __restrict__ be2){
  int idx = blockIdx.x * 256 + threadIdx.x;
  int f = idx & 63;
  const float invN = 1.f / (float)NATOM;
  float mean = sum2[f] * invN;
  float var  = fmaxf(sq2[f] * invN - mean * mean, 0.f);
  float a = g2[f] * rsqrtf(var + 1e-5f);
  float b = be2[f] - mean * a;
  float v = x[idx] + fmaf(summed[idx], a, b);
  x[idx] = softplusf_(v);
}

__global__ __launch_bounds__(256) void pool_kernel(
    const float* __restrict__ x, const int* __restrict__ cidx,
    float* __restrict__ crys, float* __restrict__ cnt){
  int idx = blockIdx.x * 256 + threadIdx.x;
  int n = idx >> 6, f = idx & 63;
  int c = cidx[n];
  atomicAdd(&crys[c * FD + f], x[idx]);
  if (f == 0) atomicAdd(&cnt[c], 1.f);
}

__global__ __launch_bounds__(128) void head_kernel(
    const float* __restrict__ crys, const float* __restrict__ cnt,
    const float* __restrict__ W_fc, const float* __restrict__ b_fc,
    const float* __restrict__ W_out, const float* __restrict__ b_out,
    void* __restrict__ out, const int* __restrict__ flag){
  __shared__ float p_s[FD];
  __shared__ float red_s[HD];
  int c = blockIdx.x, tid = threadIdx.x;
  if (tid < FD){
    float ct = fmaxf(cnt[c], 1.f);
    p_s[tid] = softplusf_(crys[c * FD + tid] / ct);
  }
  __syncthreads();
  float acc = b_fc[tid];
  for (int k = 0; k < FD; k++)
    acc = fmaf(p_s[k], W_fc[k * HD + tid], acc);
  float h = softplusf_(acc);
  red_s[tid] = h * W_out[tid];
  __syncthreads();
  for (int s = HD / 2; s > 0; s >>= 1){
    if (tid < s) red_s[tid] += red_s[tid + s];
    __syncthreads();
  }
  if (tid == 0){
    float r = red_s[0] + b_out[0];
    if (*flag) ((u16*)out)[c] = f2bf(r);
    else       ((float*)out)[c] = r;
  }
}

extern "C" void kernel_launch(void* const* d_in, const int* in_sizes, int n_in,
                              void* d_out, int out_size, void* d_ws, size_t ws_size,
                              hipStream_t stream){
  if (ws_size < WS_NEED_BYTES) return;  // diagnostic: leaves d_out zeroed
  const void* atom_fea = d_in[0];
  const void* nbr_fea  = d_in[1];
  const int* nbr_idx   = (const int*)d_in[2];
  const int* cidx      = (const int*)d_in[3];

  float* ws     = (float*)d_ws;
  float* x      = ws + OFF_X;
  float* summed = ws + OFF_SUMMED;
  float* ys     = ws + OFF_YS;
  float* yn     = ws + OFF_YN;
  float* sum1   = ws + OFF_STATS;
  float* sq1    = sum1 + 128;
  float* sum2   = sq1 + 128;
  float* sq2    = sum2 + 64;
  float* crys   = ws + OFF_CRYS;
  float* cnt    = ws + OFF_CNT;
  float* wc     = ws + OFF_WCONV;
  int*   flag   = (int*)(ws + OFF_FLAG);

  detect_kernel<<<1, 64, 0, stream>>>((const u16*)nbr_fea, flag);
  struct { int in_idx; int off; int n; } cv[12] = {
    {4,  W_EMB_O,  F0D * FD}, {5,  B_EMB_O,  FD},
    {6,  W_FULL_O, 3 * 169 * F2D}, {7,  B_FULL_O, 3 * F2D},
    {8,  G1_O,     3 * F2D}, {9,  BE1_O,    3 * F2D},
    {10, G2_O,     3 * FD},  {11, BE2_O,    3 * FD},
    {12, W_FC_O,   FD * HD}, {13, B_FC_O,   HD},
    {14, W_OUT_O,  HD},      {15, B_OUT_O,  1}
  };
  for (int i = 0; i < 12; i++)
    cvt_kernel<<<(cv[i].n + 255) / 256, 256, 0, stream>>>(
        d_in[cv[i].in_idx], wc + cv[i].off, cv[i].n, flag);

  embed_kernel<<<NATOM / 4, 256, 0, stream>>>(atom_fea, wc + W_EMB_O, wc + B_EMB_O, x, flag);
  for (int i = 0; i < 3; i++){
    const float* Wf = wc + W_FULL_O + i * 169 * F2D;
    hipMemsetAsync(sum1, 0, 384 * sizeof(float), stream);
    dual_gemm<<<NATOM / 32, 256, 0, stream>>>(x, Wf, wc + B_FULL_O + i * F2D, ys, yn);
    stats_kernel<<<2048, 256, 0, stream>>>(ys, yn, nbr_fea, nbr_idx, Wf, sum1, sq1, flag);
    act_kernel<<<2048, 256, 0, stream>>>(ys, yn, nbr_fea, nbr_idx, Wf, sum1, sq1,
        wc + G1_O + i * F2D, wc + BE1_O + i * F2D, summed, sum2, sq2, flag);
    update_x_kernel<<<(NATOM * FD) / 256, 256, 0, stream>>>(x, summed, sum2, sq2,
        wc + G2_O + i * FD, wc + BE2_O + i * FD);
  }
  hipMemsetAsync(crys, 0, (NCRY * FD + NCRY) * sizeof(float), stream);
  pool_kernel<<<(NATOM * FD) / 256, 256, 0, stream>>>(x, cidx, crys, cnt);
  head_kernel<<<NCRY, 128, 0, stream>>>(crys, cnt, wc + W_FC_O, wc + B_FC_O,
      wc + W_OUT_O, wc + B_OUT_O, d_out, flag);
}

// Round 4
// 1489.910 us; speedup vs baseline: 1.3332x; 1.3332x over previous
//
#include <hip/hip_runtime.h>
#include <hip/hip_bf16.h>

// CGCNN forward, decomposition form:
//   gated[n,m,:] = ys[n,:] + yn[nbr[n,m],:] + bond[n,m,:]@W3
// with ys = x@W1 + b, yn = x@W2  (W1=Wf[0:64], W2=Wf[64:128], W3=Wf[128:169]).
// R4: __launch_bounds__(256,2) on hot kernels — R3's VGPR_Count=72 vs 82-float
// per-lane weight arrays proved the w0/w1 arrays were spilled to scratch
// (~15TB/pass private reload traffic = the whole 316us). Also: vectorized flat
// LDS bond staging, fast transcendentals, fused weight-convert kernel.

#define NATOM 60000
#define MNBR  12
#define F0D   92
#define FBD   41
#define FD    64
#define F2D   128
#define NCRY  2000
#define HD    128

// ws layout (floats)
#define OFF_X      0ull
#define OFF_SUMMED 3840000ull
#define OFF_YS     7680000ull      // crys/cnt overlay here after conv layers
#define OFF_CRYS   7680000ull
#define OFF_CNT    7808000ull
#define OFF_YN     15360000ull
#define OFF_STATS  23040000ull     // sum1[128] sq1[128] sum2[64] sq2[64]
#define OFF_WCONV  23040384ull     // 80833 floats of converted weights
#define OFF_FLAG   23121218ull
#define WS_NEED_BYTES ((23121220ull) * 4ull)

// offsets inside wconv (contiguous regions)
#define W_EMB_O  0
#define B_EMB_O  5888
#define W_FULL_O 5952
#define B_FULL_O 70848
#define G1_O     71232
#define BE1_O    71616
#define G2_O     72000
#define BE2_O    72192
#define W_FC_O   72384
#define B_FC_O   80576
#define W_OUT_O  80704
#define B_OUT_O  80832
#define WC_TOTAL 80833

typedef unsigned short u16;

__device__ __forceinline__ float bf2f(u16 u){
  union { unsigned int i; float f; } v; v.i = ((unsigned int)u) << 16; return v.f;
}
__device__ __forceinline__ u16 f2bf(float f){
  union { float f; unsigned int i; } v; v.f = f;
  unsigned int x = v.i;
  return (u16)((x + 0x7FFFu + ((x >> 16) & 1u)) >> 16);
}
// precise versions (head / small kernels)
__device__ __forceinline__ float softplusf_(float x){
  return fmaxf(x, 0.f) + log1pf(expf(-fabsf(x)));
}
// fast versions (hot loop; err ~1e-6 vs 1.16e-2 threshold)
__device__ __forceinline__ float softplus_fast(float x){
  return fmaxf(x, 0.f) + __logf(1.f + __expf(-fabsf(x)));
}
__device__ __forceinline__ float sigmoid_fast(float x){
  return __builtin_amdgcn_rcpf(1.f + __expf(-x));
}

// Decide dtype of float inputs (1 = bf16, 0 = fp32). See R3 notes.
__global__ __launch_bounds__(64) void detect_kernel(
    const u16* __restrict__ data, int* __restrict__ flag){
  int tid = threadIdx.x;
  float v = bf2f(data[tid * 2]);
  float av = fabsf(v);
  bool sane = (av > 1e-6f) && (av < 100.f);
  unsigned long long m = __ballot(sane);
  if (tid == 0) *flag = (__popcll(m) >= 32) ? 1 : 0;
}

struct CvtArgs {
  const void* src[12];
  int start[13];   // cumulative dst offsets; start[12] = WC_TOTAL
};

// One fused kernel converts all 12 weight tensors to canonical fp32.
__global__ __launch_bounds__(256) void cvt_all_kernel(
    CvtArgs a, float* __restrict__ dst, const int* __restrict__ flag){
  int i = blockIdx.x * 256 + threadIdx.x;
  if (i >= WC_TOTAL) return;
  int r = 0;
  while (i >= a.start[r + 1]) r++;
  int rel = i - a.start[r];
  if (*flag) dst[i] = bf2f(((const u16*)a.src[r])[rel]);
  else       dst[i] = ((const float*)a.src[r])[rel];
}

// x = atom_fea @ W_emb + b_emb   (60000x92 @ 92x64)
__global__ __launch_bounds__(256) void embed_kernel(
    const void* __restrict__ atom_fea, const float* __restrict__ W_emb,
    const float* __restrict__ b_emb, float* __restrict__ x,
    const int* __restrict__ flag){
  int tid = threadIdx.x;
  int n = blockIdx.x * 4 + (tid >> 6);
  int f = tid & 63;
  float acc = b_emb[f];
  if (*flag){
    const u16* arow = (const u16*)atom_fea + n * F0D;
    for (int k = 0; k < F0D; k++)
      acc = fmaf(bf2f(arow[k]), W_emb[k * FD + f], acc);
  } else {
    const float* arow = (const float*)atom_fea + n * F0D;
    for (int k = 0; k < F0D; k++)
      acc = fmaf(arow[k], W_emb[k * FD + f], acc);
  }
  x[n * FD + f] = acc;
}

// ys = x@W1 + b ; yn = x@W2.  4 waves: (ys|yn) x (cols 0-63|64-127).
__global__ __launch_bounds__(256, 2) void dual_gemm(
    const float* __restrict__ x, const float* __restrict__ Wf,
    const float* __restrict__ bfull, float* __restrict__ ys, float* __restrict__ yn){
  __shared__ float x_s[32 * 64];
  int tid = threadIdx.x;
  int wv = tid >> 6, j = tid & 63;
  int col = ((wv & 1) << 6) + j;
  int krow0 = (wv >> 1) << 6;
  float w[64];
  #pragma unroll
  for (int k = 0; k < 64; k++) w[k] = Wf[(krow0 + k) * F2D + col];
  float bias = (wv >> 1) ? 0.f : bfull[col];
  float* out = (wv >> 1) ? yn : ys;
  int a0 = blockIdx.x * 32;
  for (int i = tid; i < 512; i += 256)
    ((float4*)x_s)[i] = ((const float4*)(x + a0 * 64))[i];
  __syncthreads();
  for (int a = 0; a < 32; a++){
    float acc = bias;
    const float4* xr = (const float4*)&x_s[a * 64];
    #pragma unroll
    for (int kk = 0; kk < 16; kk++){
      float4 xv = xr[kk];
      acc = fmaf(xv.x, w[4*kk+0], acc);
      acc = fmaf(xv.y, w[4*kk+1], acc);
      acc = fmaf(xv.z, w[4*kk+2], acc);
      acc = fmaf(xv.w, w[4*kk+3], acc);
    }
    out[(a0 + a) * F2D + col] = acc;
  }
}

// Stage 4 atoms' bond rows (4*492 elems) into flat LDS, vectorized x4.
__device__ __forceinline__ void stage_bonds(
    float* bond_all, const void* nbr_fea, int base, int tid, int isbf){
  if (isbf){
    const ushort4* src = (const ushort4*)((const u16*)nbr_fea + (long long)base * 492);
    for (int i4 = tid; i4 < 492; i4 += 256){
      ushort4 u = src[i4];
      float4 f; f.x = bf2f(u.x); f.y = bf2f(u.y); f.z = bf2f(u.z); f.w = bf2f(u.w);
      ((float4*)bond_all)[i4] = f;
    }
  } else {
    const float4* src = (const float4*)((const float*)nbr_fea + (long long)base * 492);
    for (int i4 = tid; i4 < 492; i4 += 256)
      ((float4*)bond_all)[i4] = src[i4];
  }
}

// Pass 1: BN1 column stats of g = ys[n]+yn[nb]+bond@W3 over all edges.
__global__ __launch_bounds__(256, 2) void stats_kernel(
    const float* __restrict__ ys, const float* __restrict__ yn,
    const void* __restrict__ nbr_fea, const int* __restrict__ nbr_idx,
    const float* __restrict__ Wf, float* __restrict__ sum1, float* __restrict__ sq1,
    const int* __restrict__ flag){
  __shared__ __align__(16) float bond_all[4 * 492];
  __shared__ float sum_s[F2D], sq_s[F2D];
  int tid = threadIdx.x, wv = tid >> 6, j = tid & 63;
  const int isbf = *flag;
  if (tid < F2D){ sum_s[tid] = 0.f; sq_s[tid] = 0.f; }
  float w0[41], w1[41];
  #pragma unroll
  for (int k = 0; k < 41; k++){
    w0[k] = Wf[(128 + k) * F2D + j];
    w1[k] = Wf[(128 + k) * F2D + 64 + j];
  }
  float s0 = 0.f, q0 = 0.f, s1 = 0.f, q1 = 0.f;
  for (int base = blockIdx.x * 4; base < NATOM; base += gridDim.x * 4){
    __syncthreads();
    stage_bonds(bond_all, nbr_fea, base, tid, isbf);
    __syncthreads();
    int a = base + wv;
    const float* ysr = ys + a * F2D;
    const float* bp = &bond_all[wv * 492];
    float y0 = ysr[j], y1 = ysr[64 + j];
    #pragma unroll
    for (int m = 0; m < MNBR; m++){
      int nb = nbr_idx[a * MNBR + m];
      const float* ynr = yn + nb * F2D;
      float g0 = y0 + ynr[j];
      float g1 = y1 + ynr[64 + j];
      #pragma unroll
      for (int k = 0; k < 41; k++){
        float b = bp[m * 41 + k];
        g0 = fmaf(b, w0[k], g0);
        g1 = fmaf(b, w1[k], g1);
      }
      s0 += g0; q0 = fmaf(g0, g0, q0);
      s1 += g1; q1 = fmaf(g1, g1, q1);
    }
  }
  atomicAdd(&sum_s[j], s0);      atomicAdd(&sum_s[64 + j], s1);
  atomicAdd(&sq_s[j],  q0);      atomicAdd(&sq_s[64 + j],  q1);
  __syncthreads();
  if (tid < F2D){ atomicAdd(&sum1[tid], sum_s[tid]); atomicAdd(&sq1[tid], sq_s[tid]); }
}

// Pass 2: recompute g, BN1 affine + sigmoid*softplus, sum over m -> summed;
// accumulate BN2 stats.
__global__ __launch_bounds__(256, 2) void act_kernel(
    const float* __restrict__ ys, const float* __restrict__ yn,
    const void* __restrict__ nbr_fea, const int* __restrict__ nbr_idx,
    const float* __restrict__ Wf, const float* __restrict__ sum1,
    const float* __restrict__ sq1, const float* __restrict__ g1,
    const float* __restrict__ be1, float* __restrict__ summed,
    float* __restrict__ sum2, float* __restrict__ sq2,
    const int* __restrict__ flag){
  __shared__ __align__(16) float bond_all[4 * 492];
  __shared__ float s2_s[FD], q2_s[FD];
  int tid = threadIdx.x, wv = tid >> 6, j = tid & 63;
  const int isbf = *flag;
  if (tid < FD){ s2_s[tid] = 0.f; q2_s[tid] = 0.f; }
  float w0[41], w1[41];
  #pragma unroll
  for (int k = 0; k < 41; k++){
    w0[k] = Wf[(128 + k) * F2D + j];
    w1[k] = Wf[(128 + k) * F2D + 64 + j];
  }
  const float invR = 1.f / (float)(NATOM * MNBR);
  float m0 = sum1[j] * invR;
  float v0 = fmaxf(sq1[j] * invR - m0 * m0, 0.f);
  float A0 = g1[j] * rsqrtf(v0 + 1e-5f);
  float B0 = be1[j] - m0 * A0;
  float m1 = sum1[64 + j] * invR;
  float v1 = fmaxf(sq1[64 + j] * invR - m1 * m1, 0.f);
  float A1 = g1[64 + j] * rsqrtf(v1 + 1e-5f);
  float B1 = be1[64 + j] - m1 * A1;
  float s2 = 0.f, q2 = 0.f;
  for (int base = blockIdx.x * 4; base < NATOM; base += gridDim.x * 4){
    __syncthreads();
    stage_bonds(bond_all, nbr_fea, base, tid, isbf);
    __syncthreads();
    int a = base + wv;
    const float* ysr = ys + a * F2D;
    const float* bp = &bond_all[wv * 492];
    float y0 = ysr[j], y1 = ysr[64 + j];
    float p = 0.f;
    #pragma unroll
    for (int m = 0; m < MNBR; m++){
      int nb = nbr_idx[a * MNBR + m];
      const float* ynr = yn + nb * F2D;
      float g0 = y0 + ynr[j];
      float g1v = y1 + ynr[64 + j];
      #pragma unroll
      for (int k = 0; k < 41; k++){
        float b = bp[m * 41 + k];
        g0  = fmaf(b, w0[k], g0);
        g1v = fmaf(b, w1[k], g1v);
      }
      float u = fmaf(g0, A0, B0);
      float v = fmaf(g1v, A1, B1);
      p = fmaf(sigmoid_fast(u), softplus_fast(v), p);
    }
    summed[a * FD + j] = p;
    s2 += p; q2 = fmaf(p, p, q2);
  }
  atomicAdd(&s2_s[j], s2);
  atomicAdd(&q2_s[j], q2);
  __syncthreads();
  if (tid < FD){ atomicAdd(&sum2[tid], s2_s[tid]); atomicAdd(&sq2[tid], q2_s[tid]); }
}

// x = softplus(x + bn2(summed))
__global__ __launch_bounds__(256) void update_x_kernel(
    float* __restrict__ x, const float* __restrict__ summed,
    const float* __restrict__ sum2, const float* __restrict__ sq2,
    const float* __restrict__ g2, const float* __restrict__ be2){
  int idx = blockIdx.x * 256 + threadIdx.x;
  int f = idx & 63;
  const float invN = 1.f / (float)NATOM;
  float mean = sum2[f] * invN;
  float var  = fmaxf(sq2[f] * invN - mean * mean, 0.f);
  float a = g2[f] * rsqrtf(var + 1e-5f);
  float b = be2[f] - mean * a;
  float v = x[idx] + fmaf(summed[idx], a, b);
  x[idx] = softplusf_(v);
}

__global__ __launch_bounds__(256) void pool_kernel(
    const float* __restrict__ x, const int* __restrict__ cidx,
    float* __restrict__ crys, float* __restrict__ cnt){
  int idx = blockIdx.x * 256 + threadIdx.x;
  int n = idx >> 6, f = idx & 63;
  int c = cidx[n];
  atomicAdd(&crys[c * FD + f], x[idx]);
  if (f == 0) atomicAdd(&cnt[c], 1.f);
}

__global__ __launch_bounds__(128) void head_kernel(
    const float* __restrict__ crys, const float* __restrict__ cnt,
    const float* __restrict__ W_fc, const float* __restrict__ b_fc,
    const float* __restrict__ W_out, const float* __restrict__ b_out,
    void* __restrict__ out, const int* __restrict__ flag){
  __shared__ float p_s[FD];
  __shared__ float red_s[HD];
  int c = blockIdx.x, tid = threadIdx.x;
  if (tid < FD){
    float ct = fmaxf(cnt[c], 1.f);
    p_s[tid] = softplusf_(crys[c * FD + tid] / ct);
  }
  __syncthreads();
  float acc = b_fc[tid];
  for (int k = 0; k < FD; k++)
    acc = fmaf(p_s[k], W_fc[k * HD + tid], acc);
  float h = softplusf_(acc);
  red_s[tid] = h * W_out[tid];
  __syncthreads();
  for (int s = HD / 2; s > 0; s >>= 1){
    if (tid < s) red_s[tid] += red_s[tid + s];
    __syncthreads();
  }
  if (tid == 0){
    float r = red_s[0] + b_out[0];
    if (*flag) ((u16*)out)[c] = f2bf(r);
    else       ((float*)out)[c] = r;
  }
}

extern "C" void kernel_launch(void* const* d_in, const int* in_sizes, int n_in,
                              void* d_out, int out_size, void* d_ws, size_t ws_size,
                              hipStream_t stream){
  if (ws_size < WS_NEED_BYTES) return;  // diagnostic: leaves d_out zeroed
  const void* atom_fea = d_in[0];
  const void* nbr_fea  = d_in[1];
  const int* nbr_idx   = (const int*)d_in[2];
  const int* cidx      = (const int*)d_in[3];

  float* ws     = (float*)d_ws;
  float* x      = ws + OFF_X;
  float* summed = ws + OFF_SUMMED;
  float* ys     = ws + OFF_YS;
  float* yn     = ws + OFF_YN;
  float* sum1   = ws + OFF_STATS;
  float* sq1    = sum1 + 128;
  float* sum2   = sq1 + 128;
  float* sq2    = sum2 + 64;
  float* crys   = ws + OFF_CRYS;
  float* cnt    = ws + OFF_CNT;
  float* wc     = ws + OFF_WCONV;
  int*   flag   = (int*)(ws + OFF_FLAG);

  detect_kernel<<<1, 64, 0, stream>>>((const u16*)nbr_fea, flag);
  CvtArgs ca;
  const int srcidx[12] = {4,5,6,7,8,9,10,11,12,13,14,15};
  const int starts[13] = {W_EMB_O, B_EMB_O, W_FULL_O, B_FULL_O, G1_O, BE1_O,
                          G2_O, BE2_O, W_FC_O, B_FC_O, W_OUT_O, B_OUT_O, WC_TOTAL};
  for (int i = 0; i < 12; i++){ ca.src[i] = d_in[srcidx[i]]; ca.start[i] = starts[i]; }
  ca.start[12] = WC_TOTAL;
  cvt_all_kernel<<<(WC_TOTAL + 255) / 256, 256, 0, stream>>>(ca, wc, flag);

  embed_kernel<<<NATOM / 4, 256, 0, stream>>>(atom_fea, wc + W_EMB_O, wc + B_EMB_O, x, flag);
  for (int i = 0; i < 3; i++){
    const float* Wf = wc + W_FULL_O + i * 169 * F2D;
    hipMemsetAsync(sum1, 0, 384 * sizeof(float), stream);
    dual_gemm<<<NATOM / 32, 256, 0, stream>>>(x, Wf, wc + B_FULL_O + i * F2D, ys, yn);
    stats_kernel<<<2048, 256, 0, stream>>>(ys, yn, nbr_fea, nbr_idx, Wf, sum1, sq1, flag);
    act_kernel<<<2048, 256, 0, stream>>>(ys, yn, nbr_fea, nbr_idx, Wf, sum1, sq1,
        wc + G1_O + i * F2D, wc + BE1_O + i * F2D, summed, sum2, sq2, flag);
    update_x_kernel<<<(NATOM * FD) / 256, 256, 0, stream>>>(x, summed, sum2, sq2,
        wc + G2_O + i * FD, wc + BE2_O + i * FD);
  }
  hipMemsetAsync(crys, 0, (NCRY * FD + NCRY) * sizeof(float), stream);
  pool_kernel<<<(NATOM * FD) / 256, 256, 0, stream>>>(x, cidx, crys, cnt);
  head_kernel<<<NCRY, 128, 0, stream>>>(crys, cnt, wc + W_FC_O, wc + B_FC_O,
      wc + W_OUT_O, wc + B_OUT_O, d_out, flag);
}

// Round 6
// 1173.468 us; speedup vs baseline: 1.6928x; 1.2697x over previous
//
#include <hip/hip_runtime.h>
#include <hip/hip_bf16.h>

// CGCNN forward. R6 == R5 (MFMA conv GEMM) with the ws layout bug fixed:
// wbf needs 73728 u16 = 36864 float slots; R5 reserved only 18432 (divided
// by 4 not 2), so build_bfrag clobbered flag + 73KB of heap past ws -> NaN.
//   g[e,:] = [x[n(e)] | x[nb(e)] | bond(e)] @ Wf + b   (K=169 pad 192, N=128)
// computed twice per layer (stats pass, act pass); super-tile = 48 edges.

#define NATOM 60000
#define MNBR  12
#define F0D   92
#define FBD   41
#define FD    64
#define F2D   128
#define NCRY  2000
#define HD    128
#define NSUP  15000          // 720000 edges / 48

// ws layout (float units)
#define OFF_X      0ull          // 3,840,000 f32
#define OFF_XH     3840000ull    // 3,840,000 u16 (1,920,000 f slots)
#define OFF_SUMMED 5760000ull    // 3,840,000 f32
#define OFF_STATS  9600000ull    // sum1[128] sq1[128] sum2[64] sq2[64]
#define OFF_CRYS   9600384ull    // 128,000
#define OFF_CNT    9728384ull    // 2,000
#define OFF_WCONV  9730384ull    // 80,833 f32 canonical weights
#define OFF_WBF    9811220ull    // 73,728 u16 = 36,864 f slots (16B aligned)
#define OFF_FLAG   9848084ull    // FIXED (was 9829652 = mid-wbf)
#define WS_NEED_BYTES (9848085ull * 4ull)

// offsets inside wconv
#define W_EMB_O  0
#define B_EMB_O  5888
#define W_FULL_O 5952
#define B_FULL_O 70848
#define G1_O     71232
#define BE1_O    71616
#define G2_O     72000
#define BE2_O    72192
#define W_FC_O   72384
#define B_FC_O   80576
#define W_OUT_O  80704
#define B_OUT_O  80832
#define WC_TOTAL 80833

typedef unsigned short u16;
typedef __attribute__((ext_vector_type(8))) short bf16x8;   // 8 bf16 = 4 VGPR
typedef __attribute__((ext_vector_type(4))) float f32x4;

__device__ __forceinline__ float bf2f(u16 u){
  union { unsigned int i; float f; } v; v.i = ((unsigned int)u) << 16; return v.f;
}
__device__ __forceinline__ u16 f2bf(float f){
  union { float f; unsigned int i; } v; v.f = f;
  unsigned int x = v.i;
  return (u16)((x + 0x7FFFu + ((x >> 16) & 1u)) >> 16);
}
__device__ __forceinline__ float softplusf_(float x){
  return fmaxf(x, 0.f) + log1pf(expf(-fabsf(x)));
}
__device__ __forceinline__ float softplus_fast(float x){
  return fmaxf(x, 0.f) + __logf(1.f + __expf(-fabsf(x)));
}
__device__ __forceinline__ float sigmoid_fast(float x){
  return __builtin_amdgcn_rcpf(1.f + __expf(-x));
}

__global__ __launch_bounds__(64) void detect_kernel(
    const u16* __restrict__ data, int* __restrict__ flag){
  int tid = threadIdx.x;
  float v = bf2f(data[tid * 2]);
  float av = fabsf(v);
  bool sane = (av > 1e-6f) && (av < 100.f);
  unsigned long long m = __ballot(sane);
  if (tid == 0) *flag = (__popcll(m) >= 32) ? 1 : 0;
}

struct CvtArgs {
  const void* src[12];
  int start[13];
};

__global__ __launch_bounds__(256) void cvt_all_kernel(
    CvtArgs a, float* __restrict__ dst, const int* __restrict__ flag){
  int i = blockIdx.x * 256 + threadIdx.x;
  if (i >= WC_TOTAL) return;
  int r = 0;
  while (i >= a.start[r + 1]) r++;
  int rel = i - a.start[r];
  if (*flag) dst[i] = bf2f(((const u16*)a.src[r])[rel]);
  else       dst[i] = ((const float*)a.src[r])[rel];
}

// Build MFMA B-fragments for all 3 layers from fp32 Wf.
// wbf[((layer*6 + c)*8 + nt)*64 + lane][i] = bf16(Wf[k=c*32+(lane>>4)*8+i][nt*16+(lane&15)])
__global__ __launch_bounds__(256) void build_bfrag(
    const float* __restrict__ wfull, u16* __restrict__ wbf){
  int t = blockIdx.x * 256 + threadIdx.x;
  if (t >= 3 * 6 * 8 * 64) return;
  int lane = t & 63, nt = (t >> 6) & 7, c = (t >> 9) % 6, layer = t / 3072;
  int q = lane >> 4, nloc = lane & 15;
  u16 vals[8];
  #pragma unroll
  for (int i = 0; i < 8; i++){
    int k = c * 32 + q * 8 + i;
    float v = (k < 169) ? wfull[layer * 169 * F2D + k * F2D + nt * 16 + nloc] : 0.f;
    vals[i] = f2bf(v);
  }
  *(uint4*)&wbf[(size_t)t * 8] = *(uint4*)vals;
}

// x = atom_fea @ W_emb + b_emb; also bf16 mirror xh.
__global__ __launch_bounds__(256) void embed_kernel(
    const void* __restrict__ atom_fea, const float* __restrict__ W_emb,
    const float* __restrict__ b_emb, float* __restrict__ x,
    u16* __restrict__ xh, const int* __restrict__ flag){
  int tid = threadIdx.x;
  int n = blockIdx.x * 4 + (tid >> 6);
  int f = tid & 63;
  float acc = b_emb[f];
  if (*flag){
    const u16* arow = (const u16*)atom_fea + n * F0D;
    for (int k = 0; k < F0D; k++)
      acc = fmaf(bf2f(arow[k]), W_emb[k * FD + f], acc);
  } else {
    const float* arow = (const float*)atom_fea + n * F0D;
    for (int k = 0; k < F0D; k++)
      acc = fmaf(arow[k], W_emb[k * FD + f], acc);
  }
  x[n * FD + f] = acc;
  xh[n * FD + f] = f2bf(acc);
}

// The MFMA conv pass. ACT=0: BN1 stats only. ACT=1: g -> LDS, fused
// sigmoid*softplus, sum over m -> summed, BN2 stats.
template<int ACT>
__global__ __launch_bounds__(256, 3) void conv_mfma(
    const u16* __restrict__ xh, const void* __restrict__ nbr_fea,
    const int* __restrict__ nbr_idx, const u16* __restrict__ wbf_l,
    const float* __restrict__ bfull, const float* __restrict__ sum1,
    const float* __restrict__ sq1, const float* __restrict__ g1,
    const float* __restrict__ be1, float* __restrict__ summed,
    float* __restrict__ o_sum, float* __restrict__ o_sq,
    const int* __restrict__ flag){
  extern __shared__ char smem[];
  u16*   bond = (u16*)smem;                       // 2048 u16 (48*41 used + pad)
  float* gbuf = (float*)(smem + 4096);            // ACT: 48*128 f32
  float* redS = ACT ? (gbuf + 48 * 128) : gbuf;
  float* redQ = redS + (ACT ? 64 : 128);

  const int tid = threadIdx.x;
  const int w = tid >> 6, lane = tid & 63;
  const int q = lane >> 4, nloc = lane & 15, q8 = q * 8;
  const int isbf = *flag;

  bf16x8 Bf[6][2];
  const bf16x8* Bv = (const bf16x8*)wbf_l;
  #pragma unroll
  for (int c = 0; c < 6; c++)
    #pragma unroll
    for (int t2 = 0; t2 < 2; t2++)
      Bf[c][t2] = Bv[(c * 8 + w * 2 + t2) * 64 + lane];
  float bias0 = bfull[w * 32 + nloc];
  float bias1 = bfull[w * 32 + 16 + nloc];

  float A0 = 0.f, B0 = 0.f, A1 = 0.f, B1 = 0.f;
  if (ACT){
    const float invR = 1.f / (float)(NATOM * MNBR);
    float m0 = sum1[lane] * invR;
    float v0 = fmaxf(sq1[lane] * invR - m0 * m0, 0.f);
    A0 = g1[lane] * rsqrtf(v0 + 1e-5f);  B0 = be1[lane] - m0 * A0;
    float m1 = sum1[64 + lane] * invR;
    float v1 = fmaxf(sq1[64 + lane] * invR - m1 * m1, 0.f);
    A1 = g1[64 + lane] * rsqrtf(v1 + 1e-5f);  B1 = be1[64 + lane] - m1 * A1;
  }
  float sAcc0 = 0.f, sAcc1 = 0.f, qAcc0 = 0.f, qAcc1 = 0.f;
  if (tid < (ACT ? 64 : 128)){ redS[tid] = 0.f; redQ[tid] = 0.f; }

  const bf16x8* xv = (const bf16x8*)xh;
  for (int s = blockIdx.x; s < NSUP; s += gridDim.x){
    // stage 48 edges x 41 bond feats (bf16) into LDS
    if (isbf){
      const uint4* src = (const uint4*)((const u16*)nbr_fea + (size_t)s * 1968);
      if (tid < 246) *(uint4*)&bond[tid * 8] = src[tid];
    } else {
      const float4* src = (const float4*)((const float*)nbr_fea + (size_t)s * 1968);
      for (int t = tid; t < 492; t += 256){
        float4 v = src[t];
        ushort4 o; o.x = f2bf(v.x); o.y = f2bf(v.y); o.z = f2bf(v.z); o.w = f2bf(v.w);
        *(ushort4*)&bond[t * 4] = o;
      }
    }
    __syncthreads();
    #pragma unroll
    for (int et = 0; et < 3; et++){
      int e  = s * 48 + et * 16 + nloc;
      int na = s * 4 + (et * 16 + nloc) / 12;
      int nb = nbr_idx[e];
      bf16x8 a0 = xv[na * 8 + q];       // K 0..31   (x_self)
      bf16x8 a1 = xv[na * 8 + 4 + q];   // K 32..63
      bf16x8 a2 = xv[nb * 8 + q];       // K 64..95  (x_nbr)
      bf16x8 a3 = xv[nb * 8 + 4 + q];   // K 96..127
      int ebase = (et * 16 + nloc) * 41;
      bf16x8 a4, a5;                    // K 128..191 (bond, zero-padded)
      #pragma unroll
      for (int i = 0; i < 8; i++){
        a4[i] = (short)bond[ebase + q8 + i];
        int k5 = 32 + q8 + i;
        u16 v5 = bond[ebase + ((k5 < 41) ? k5 : 0)];
        a5[i] = (k5 < 41) ? (short)v5 : (short)0;
      }
      #pragma unroll
      for (int t2 = 0; t2 < 2; t2++){
        float bs = t2 ? bias1 : bias0;
        f32x4 acc = {bs, bs, bs, bs};
        acc = __builtin_amdgcn_mfma_f32_16x16x32_bf16(a0, Bf[0][t2], acc, 0, 0, 0);
        acc = __builtin_amdgcn_mfma_f32_16x16x32_bf16(a1, Bf[1][t2], acc, 0, 0, 0);
        acc = __builtin_amdgcn_mfma_f32_16x16x32_bf16(a2, Bf[2][t2], acc, 0, 0, 0);
        acc = __builtin_amdgcn_mfma_f32_16x16x32_bf16(a3, Bf[3][t2], acc, 0, 0, 0);
        acc = __builtin_amdgcn_mfma_f32_16x16x32_bf16(a4, Bf[4][t2], acc, 0, 0, 0);
        acc = __builtin_amdgcn_mfma_f32_16x16x32_bf16(a5, Bf[5][t2], acc, 0, 0, 0);
        if (ACT){
          int col = w * 32 + t2 * 16 + nloc;
          int r0 = et * 16 + q * 4;
          gbuf[(r0 + 0) * 128 + col] = acc[0];
          gbuf[(r0 + 1) * 128 + col] = acc[1];
          gbuf[(r0 + 2) * 128 + col] = acc[2];
          gbuf[(r0 + 3) * 128 + col] = acc[3];
        } else {
          float ss = acc[0] + acc[1] + acc[2] + acc[3];
          float qq = acc[0]*acc[0] + acc[1]*acc[1] + acc[2]*acc[2] + acc[3]*acc[3];
          if (t2){ sAcc1 += ss; qAcc1 += qq; } else { sAcc0 += ss; qAcc0 += qq; }
        }
      }
    }
    if (ACT){
      __syncthreads();   // g complete
      float p = 0.f;
      #pragma unroll
      for (int m = 0; m < 12; m++){
        int el = w * 12 + m;
        float u = fmaf(gbuf[el * 128 + lane],      A0, B0);
        float v = fmaf(gbuf[el * 128 + 64 + lane], A1, B1);
        p = fmaf(sigmoid_fast(u), softplus_fast(v), p);
      }
      summed[(s * 4 + w) * 64 + lane] = p;
      sAcc0 += p;  qAcc0 = fmaf(p, p, qAcc0);
    }
    __syncthreads();   // protect bond (and gbuf) for next iteration
  }
  if (ACT){
    atomicAdd(&redS[lane], sAcc0);
    atomicAdd(&redQ[lane], qAcc0);
    __syncthreads();
    if (tid < 64){ atomicAdd(&o_sum[tid], redS[tid]); atomicAdd(&o_sq[tid], redQ[tid]); }
  } else {
    int c0 = w * 32 + nloc;
    atomicAdd(&redS[c0], sAcc0);       atomicAdd(&redQ[c0], qAcc0);
    atomicAdd(&redS[c0 + 16], sAcc1);  atomicAdd(&redQ[c0 + 16], qAcc1);
    __syncthreads();
    if (tid < 128){ atomicAdd(&o_sum[tid], redS[tid]); atomicAdd(&o_sq[tid], redQ[tid]); }
  }
}

// x = softplus(x + bn2(summed)); refresh bf16 mirror.
__global__ __launch_bounds__(256) void update_x_kernel(
    float* __restrict__ x, u16* __restrict__ xh,
    const float* __restrict__ summed,
    const float* __restrict__ sum2, const float* __restrict__ sq2,
    const float* __restrict__ g2, const float* __restrict__ be2){
  int idx = blockIdx.x * 256 + threadIdx.x;
  int f = idx & 63;
  const float invN = 1.f / (float)NATOM;
  float mean = sum2[f] * invN;
  float var  = fmaxf(sq2[f] * invN - mean * mean, 0.f);
  float a = g2[f] * rsqrtf(var + 1e-5f);
  float b = be2[f] - mean * a;
  float v = x[idx] + fmaf(summed[idx], a, b);
  float r = softplusf_(v);
  x[idx] = r;
  xh[idx] = f2bf(r);
}

__global__ __launch_bounds__(256) void pool_kernel(
    const float* __restrict__ x, const int* __restrict__ cidx,
    float* __restrict__ crys, float* __restrict__ cnt){
  int idx = blockIdx.x * 256 + threadIdx.x;
  int n = idx >> 6, f = idx & 63;
  int c = cidx[n];
  atomicAdd(&crys[c * FD + f], x[idx]);
  if (f == 0) atomicAdd(&cnt[c], 1.f);
}

__global__ __launch_bounds__(128) void head_kernel(
    const float* __restrict__ crys, const float* __restrict__ cnt,
    const float* __restrict__ W_fc, const float* __restrict__ b_fc,
    const float* __restrict__ W_out, const float* __restrict__ b_out,
    void* __restrict__ out, const int* __restrict__ flag){
  __shared__ float p_s[FD];
  __shared__ float red_s[HD];
  int c = blockIdx.x, tid = threadIdx.x;
  if (tid < FD){
    float ct = fmaxf(cnt[c], 1.f);
    p_s[tid] = softplusf_(crys[c * FD + tid] / ct);
  }
  __syncthreads();
  float acc = b_fc[tid];
  for (int k = 0; k < FD; k++)
    acc = fmaf(p_s[k], W_fc[k * HD + tid], acc);
  float h = softplusf_(acc);
  red_s[tid] = h * W_out[tid];
  __syncthreads();
  for (int s = HD / 2; s > 0; s >>= 1){
    if (tid < s) red_s[tid] += red_s[tid + s];
    __syncthreads();
  }
  if (tid == 0){
    float r = red_s[0] + b_out[0];
    if (*flag) ((u16*)out)[c] = f2bf(r);
    else       ((float*)out)[c] = r;
  }
}

extern "C" void kernel_launch(void* const* d_in, const int* in_sizes, int n_in,
                              void* d_out, int out_size, void* d_ws, size_t ws_size,
                              hipStream_t stream){
  if (ws_size < WS_NEED_BYTES) return;  // diagnostic: leaves d_out zeroed
  const void* atom_fea = d_in[0];
  const void* nbr_fea  = d_in[1];
  const int* nbr_idx   = (const int*)d_in[2];
  const int* cidx      = (const int*)d_in[3];

  float* ws     = (float*)d_ws;
  float* x      = ws + OFF_X;
  u16*   xh     = (u16*)(ws + OFF_XH);
  float* summed = ws + OFF_SUMMED;
  float* sum1   = ws + OFF_STATS;
  float* sq1    = sum1 + 128;
  float* sum2   = sq1 + 128;
  float* sq2    = sum2 + 64;
  float* crys   = ws + OFF_CRYS;
  float* cnt    = ws + OFF_CNT;
  float* wc     = ws + OFF_WCONV;
  u16*   wbf    = (u16*)(ws + OFF_WBF);
  int*   flag   = (int*)(ws + OFF_FLAG);

  detect_kernel<<<1, 64, 0, stream>>>((const u16*)nbr_fea, flag);
  CvtArgs ca;
  const int srcidx[12] = {4,5,6,7,8,9,10,11,12,13,14,15};
  const int starts[13] = {W_EMB_O, B_EMB_O, W_FULL_O, B_FULL_O, G1_O, BE1_O,
                          G2_O, BE2_O, W_FC_O, B_FC_O, W_OUT_O, B_OUT_O, WC_TOTAL};
  for (int i = 0; i < 12; i++){ ca.src[i] = d_in[srcidx[i]]; ca.start[i] = starts[i]; }
  ca.start[12] = WC_TOTAL;
  cvt_all_kernel<<<(WC_TOTAL + 255) / 256, 256, 0, stream>>>(ca, wc, flag);
  build_bfrag<<<(9216 + 255) / 256, 256, 0, stream>>>(wc + W_FULL_O, wbf);

  embed_kernel<<<NATOM / 4, 256, 0, stream>>>(atom_fea, wc + W_EMB_O, wc + B_EMB_O,
                                              x, xh, flag);
  for (int i = 0; i < 3; i++){
    const u16* wbf_l = wbf + (size_t)i * 3072 * 8;
    hipMemsetAsync(sum1, 0, 384 * sizeof(float), stream);
    conv_mfma<0><<<1024, 256, 5120, stream>>>(xh, nbr_fea, nbr_idx, wbf_l,
        wc + B_FULL_O + i * F2D, sum1, sq1, wc + G1_O + i * F2D,
        wc + BE1_O + i * F2D, summed, sum1, sq1, flag);
    conv_mfma<1><<<1024, 256, 29184, stream>>>(xh, nbr_fea, nbr_idx, wbf_l,
        wc + B_FULL_O + i * F2D, sum1, sq1, wc + G1_O + i * F2D,
        wc + BE1_O + i * F2D, summed, sum2, sq2, flag);
    update_x_kernel<<<(NATOM * FD) / 256, 256, 0, stream>>>(x, xh, summed, sum2, sq2,
        wc + G2_O + i * FD, wc + BE2_O + i * FD);
  }
  hipMemsetAsync(crys, 0, (NCRY * FD + NCRY) * sizeof(float), stream);
  pool_kernel<<<(NATOM * FD) / 256, 256, 0, stream>>>(x, cidx, crys, cnt);
  head_kernel<<<NCRY, 128, 0, stream>>>(crys, cnt, wc + W_FC_O, wc + B_FC_O,
      wc + W_OUT_O, wc + B_OUT_O, d_out, flag);
}

// Round 7
// 1100.430 us; speedup vs baseline: 1.8051x; 1.0664x over previous
//
#include <hip/hip_runtime.h>
#include <hip/hip_bf16.h>

// CGCNN forward, MFMA conv GEMM (R7).
//   g[e,:] = [x[n(e)] | x[nb(e)] | bond(e)] @ Wf + b  (K=169 pad 192, N=128)
// R7 vs R6: (1) bond A-fragments built cooperatively ONCE per supertile by
// waves 0-2 (straight from global, no raw staging) and shared via LDS b128
// reads -- kills the 4x-replicated 16-scalar-read unpack; (2) gbuf stride
// 132 kills the 4-way C-write bank conflicts (R6: 4.32M); (3) grid 3000.

#define NATOM 60000
#define MNBR  12
#define F0D   92
#define FBD   41
#define FD    64
#define F2D   128
#define NCRY  2000
#define HD    128
#define NSUP  15000          // 720000 edges / 48
#define GS    132            // gbuf row stride (floats): banks shift 16/quad

// ws layout (float units)
#define OFF_X      0ull          // 3,840,000 f32
#define OFF_XH     3840000ull    // 3,840,000 u16 (1,920,000 f slots)
#define OFF_SUMMED 5760000ull    // 3,840,000 f32
#define OFF_STATS  9600000ull    // sum1[128] sq1[128] sum2[64] sq2[64]
#define OFF_CRYS   9600384ull    // 128,000
#define OFF_CNT    9728384ull    // 2,000
#define OFF_WCONV  9730384ull    // 80,833 f32 canonical weights
#define OFF_WBF    9811220ull    // 73,728 u16 = 36,864 f slots (16B aligned)
#define OFF_FLAG   9848084ull
#define WS_NEED_BYTES (9848085ull * 4ull)

// offsets inside wconv
#define W_EMB_O  0
#define B_EMB_O  5888
#define W_FULL_O 5952
#define B_FULL_O 70848
#define G1_O     71232
#define BE1_O    71616
#define G2_O     72000
#define BE2_O    72192
#define W_FC_O   72384
#define B_FC_O   80576
#define W_OUT_O  80704
#define B_OUT_O  80832
#define WC_TOTAL 80833

typedef unsigned short u16;
typedef __attribute__((ext_vector_type(8))) short bf16x8;   // 8 bf16 = 4 VGPR
typedef __attribute__((ext_vector_type(4))) float f32x4;

__device__ __forceinline__ float bf2f(u16 u){
  union { unsigned int i; float f; } v; v.i = ((unsigned int)u) << 16; return v.f;
}
__device__ __forceinline__ u16 f2bf(float f){
  union { float f; unsigned int i; } v; v.f = f;
  unsigned int x = v.i;
  return (u16)((x + 0x7FFFu + ((x >> 16) & 1u)) >> 16);
}
__device__ __forceinline__ float softplusf_(float x){
  return fmaxf(x, 0.f) + log1pf(expf(-fabsf(x)));
}
__device__ __forceinline__ float softplus_fast(float x){
  return fmaxf(x, 0.f) + __logf(1.f + __expf(-fabsf(x)));
}
__device__ __forceinline__ float sigmoid_fast(float x){
  return __builtin_amdgcn_rcpf(1.f + __expf(-x));
}

__global__ __launch_bounds__(64) void detect_kernel(
    const u16* __restrict__ data, int* __restrict__ flag){
  int tid = threadIdx.x;
  float v = bf2f(data[tid * 2]);
  float av = fabsf(v);
  bool sane = (av > 1e-6f) && (av < 100.f);
  unsigned long long m = __ballot(sane);
  if (tid == 0) *flag = (__popcll(m) >= 32) ? 1 : 0;
}

struct CvtArgs {
  const void* src[12];
  int start[13];
};

__global__ __launch_bounds__(256) void cvt_all_kernel(
    CvtArgs a, float* __restrict__ dst, const int* __restrict__ flag){
  int i = blockIdx.x * 256 + threadIdx.x;
  if (i >= WC_TOTAL) return;
  int r = 0;
  while (i >= a.start[r + 1]) r++;
  int rel = i - a.start[r];
  if (*flag) dst[i] = bf2f(((const u16*)a.src[r])[rel]);
  else       dst[i] = ((const float*)a.src[r])[rel];
}

// Build MFMA B-fragments for all 3 layers from fp32 Wf.
__global__ __launch_bounds__(256) void build_bfrag(
    const float* __restrict__ wfull, u16* __restrict__ wbf){
  int t = blockIdx.x * 256 + threadIdx.x;
  if (t >= 3 * 6 * 8 * 64) return;
  int lane = t & 63, nt = (t >> 6) & 7, c = (t >> 9) % 6, layer = t / 3072;
  int q = lane >> 4, nloc = lane & 15;
  u16 vals[8];
  #pragma unroll
  for (int i = 0; i < 8; i++){
    int k = c * 32 + q * 8 + i;
    float v = (k < 169) ? wfull[layer * 169 * F2D + k * F2D + nt * 16 + nloc] : 0.f;
    vals[i] = f2bf(v);
  }
  *(uint4*)&wbf[(size_t)t * 8] = *(uint4*)vals;
}

// x = atom_fea @ W_emb + b_emb; also bf16 mirror xh.
__global__ __launch_bounds__(256) void embed_kernel(
    const void* __restrict__ atom_fea, const float* __restrict__ W_emb,
    const float* __restrict__ b_emb, float* __restrict__ x,
    u16* __restrict__ xh, const int* __restrict__ flag){
  int tid = threadIdx.x;
  int n = blockIdx.x * 4 + (tid >> 6);
  int f = tid & 63;
  float acc = b_emb[f];
  if (*flag){
    const u16* arow = (const u16*)atom_fea + n * F0D;
    for (int k = 0; k < F0D; k++)
      acc = fmaf(bf2f(arow[k]), W_emb[k * FD + f], acc);
  } else {
    const float* arow = (const float*)atom_fea + n * F0D;
    for (int k = 0; k < F0D; k++)
      acc = fmaf(arow[k], W_emb[k * FD + f], acc);
  }
  x[n * FD + f] = acc;
  xh[n * FD + f] = f2bf(acc);
}

// MFMA conv pass. ACT=0: BN1 stats only. ACT=1: g -> LDS (stride GS),
// fused sigmoid*softplus, sum over m -> summed, BN2 stats.
// LDS: fragA 6144B | (ACT) gbuf 48*GS*4 | red 2*(64|128)*4
template<int ACT>
__global__ __launch_bounds__(256, 3) void conv_mfma(
    const u16* __restrict__ xh, const void* __restrict__ nbr_fea,
    const int* __restrict__ nbr_idx, const u16* __restrict__ wbf_l,
    const float* __restrict__ bfull, const float* __restrict__ sum1,
    const float* __restrict__ sq1, const float* __restrict__ g1,
    const float* __restrict__ be1, float* __restrict__ summed,
    float* __restrict__ o_sum, float* __restrict__ o_sq,
    const int* __restrict__ flag){
  extern __shared__ char smem[];
  u16*   fragA = (u16*)smem;                         // 6 * 512 u16
  float* gbuf  = (float*)(smem + 6144);              // ACT only: 48*GS
  float* redS  = ACT ? (gbuf + 48 * GS) : (float*)(smem + 6144);
  float* redQ  = redS + (ACT ? 64 : 128);

  const int tid = threadIdx.x;
  const int w = tid >> 6, lane = tid & 63;
  const int q = lane >> 4, nloc = lane & 15, q8 = q * 8;
  const int isbf = *flag;

  bf16x8 Bf[6][2];
  const bf16x8* Bv = (const bf16x8*)wbf_l;
  #pragma unroll
  for (int c = 0; c < 6; c++)
    #pragma unroll
    for (int t2 = 0; t2 < 2; t2++)
      Bf[c][t2] = Bv[(c * 8 + w * 2 + t2) * 64 + lane];
  float bias0 = bfull[w * 32 + nloc];
  float bias1 = bfull[w * 32 + 16 + nloc];

  float A0 = 0.f, B0 = 0.f, A1 = 0.f, B1 = 0.f;
  if (ACT){
    const float invR = 1.f / (float)(NATOM * MNBR);
    float m0 = sum1[lane] * invR;
    float v0 = fmaxf(sq1[lane] * invR - m0 * m0, 0.f);
    A0 = g1[lane] * rsqrtf(v0 + 1e-5f);  B0 = be1[lane] - m0 * A0;
    float m1 = sum1[64 + lane] * invR;
    float v1 = fmaxf(sq1[64 + lane] * invR - m1 * m1, 0.f);
    A1 = g1[64 + lane] * rsqrtf(v1 + 1e-5f);  B1 = be1[64 + lane] - m1 * A1;
  }
  float sAcc0 = 0.f, sAcc1 = 0.f, qAcc0 = 0.f, qAcc1 = 0.f;
  if (tid < (ACT ? 64 : 128)){ redS[tid] = 0.f; redQ[tid] = 0.f; }

  const bf16x8* xv = (const bf16x8*)xh;
  for (int s = blockIdx.x; s < NSUP; s += gridDim.x){
    // waves 0-2: build bond A-fragments for et = w, straight from global.
    if (w < 3){
      size_t eg = (size_t)(s * 48 + w * 16 + nloc);
      u16 v4[8], v5[8];
      if (isbf){
        const u16* br = (const u16*)nbr_fea + eg * 41;
        #pragma unroll
        for (int i = 0; i < 8; i++) v4[i] = br[q8 + i];
        #pragma unroll
        for (int i = 0; i < 8; i++){
          int k5 = 32 + q8 + i;
          v5[i] = (k5 < 41) ? br[(k5 < 41) ? k5 : 0] : (u16)0;
        }
      } else {
        const float* br = (const float*)nbr_fea + eg * 41;
        #pragma unroll
        for (int i = 0; i < 8; i++) v4[i] = f2bf(br[q8 + i]);
        #pragma unroll
        for (int i = 0; i < 8; i++){
          int k5 = 32 + q8 + i;
          v5[i] = (k5 < 41) ? f2bf(br[(k5 < 41) ? k5 : 0]) : (u16)0;
        }
      }
      *(uint4*)&fragA[(w * 2 + 0) * 512 + lane * 8] = *(uint4*)v4;
      *(uint4*)&fragA[(w * 2 + 1) * 512 + lane * 8] = *(uint4*)v5;
    }
    // prefetch neighbor indices for all 3 et tiles (latency hidden by barrier)
    int e0 = s * 48 + nloc;
    int nb0 = nbr_idx[e0], nb1 = nbr_idx[e0 + 16], nb2 = nbr_idx[e0 + 32];
    __syncthreads();
    #pragma unroll
    for (int et = 0; et < 3; et++){
      int nb = (et == 0) ? nb0 : (et == 1) ? nb1 : nb2;
      int na = s * 4 + (et * 16 + nloc) / 12;
      bf16x8 a0 = xv[na * 8 + q];       // K 0..31   (x_self)
      bf16x8 a1 = xv[na * 8 + 4 + q];   // K 32..63
      bf16x8 a2 = xv[nb * 8 + q];       // K 64..95  (x_nbr)
      bf16x8 a3 = xv[nb * 8 + 4 + q];   // K 96..127
      bf16x8 a4 = *(bf16x8*)&fragA[(et * 2 + 0) * 512 + lane * 8];
      bf16x8 a5 = *(bf16x8*)&fragA[(et * 2 + 1) * 512 + lane * 8];
      #pragma unroll
      for (int t2 = 0; t2 < 2; t2++){
        float bs = t2 ? bias1 : bias0;
        f32x4 acc = {bs, bs, bs, bs};
        acc = __builtin_amdgcn_mfma_f32_16x16x32_bf16(a0, Bf[0][t2], acc, 0, 0, 0);
        acc = __builtin_amdgcn_mfma_f32_16x16x32_bf16(a1, Bf[1][t2], acc, 0, 0, 0);
        acc = __builtin_amdgcn_mfma_f32_16x16x32_bf16(a2, Bf[2][t2], acc, 0, 0, 0);
        acc = __builtin_amdgcn_mfma_f32_16x16x32_bf16(a3, Bf[3][t2], acc, 0, 0, 0);
        acc = __builtin_amdgcn_mfma_f32_16x16x32_bf16(a4, Bf[4][t2], acc, 0, 0, 0);
        acc = __builtin_amdgcn_mfma_f32_16x16x32_bf16(a5, Bf[5][t2], acc, 0, 0, 0);
        if (ACT){
          int col = w * 32 + t2 * 16 + nloc;
          int r0 = et * 16 + q * 4;
          gbuf[(r0 + 0) * GS + col] = acc[0];
          gbuf[(r0 + 1) * GS + col] = acc[1];
          gbuf[(r0 + 2) * GS + col] = acc[2];
          gbuf[(r0 + 3) * GS + col] = acc[3];
        } else {
          float ss = acc[0] + acc[1] + acc[2] + acc[3];
          float qq = acc[0]*acc[0] + acc[1]*acc[1] + acc[2]*acc[2] + acc[3]*acc[3];
          if (t2){ sAcc1 += ss; qAcc1 += qq; } else { sAcc0 += ss; qAcc0 += qq; }
        }
      }
    }
    if (ACT){
      __syncthreads();   // g complete
      float p = 0.f;
      #pragma unroll
      for (int m = 0; m < 12; m++){
        int el = w * 12 + m;
        float u = fmaf(gbuf[el * GS + lane],      A0, B0);
        float v = fmaf(gbuf[el * GS + 64 + lane], A1, B1);
        p = fmaf(sigmoid_fast(u), softplus_fast(v), p);
      }
      summed[(s * 4 + w) * 64 + lane] = p;
      sAcc0 += p;  qAcc0 = fmaf(p, p, qAcc0);
    }
    __syncthreads();   // protect fragA (and gbuf) for next iteration
  }
  if (ACT){
    atomicAdd(&redS[lane], sAcc0);
    atomicAdd(&redQ[lane], qAcc0);
    __syncthreads();
    if (tid < 64){ atomicAdd(&o_sum[tid], redS[tid]); atomicAdd(&o_sq[tid], redQ[tid]); }
  } else {
    int c0 = w * 32 + nloc;
    atomicAdd(&redS[c0], sAcc0);       atomicAdd(&redQ[c0], qAcc0);
    atomicAdd(&redS[c0 + 16], sAcc1);  atomicAdd(&redQ[c0 + 16], qAcc1);
    __syncthreads();
    if (tid < 128){ atomicAdd(&o_sum[tid], redS[tid]); atomicAdd(&o_sq[tid], redQ[tid]); }
  }
}

// x = softplus(x + bn2(summed)); refresh bf16 mirror.
__global__ __launch_bounds__(256) void update_x_kernel(
    float* __restrict__ x, u16* __restrict__ xh,
    const float* __restrict__ summed,
    const float* __restrict__ sum2, const float* __restrict__ sq2,
    const float* __restrict__ g2, const float* __restrict__ be2){
  int idx = blockIdx.x * 256 + threadIdx.x;
  int f = idx & 63;
  const float invN = 1.f / (float)NATOM;
  float mean = sum2[f] * invN;
  float var  = fmaxf(sq2[f] * invN - mean * mean, 0.f);
  float a = g2[f] * rsqrtf(var + 1e-5f);
  float b = be2[f] - mean * a;
  float v = x[idx] + fmaf(summed[idx], a, b);
  float r = softplusf_(v);
  x[idx] = r;
  xh[idx] = f2bf(r);
}

__global__ __launch_bounds__(256) void pool_kernel(
    const float* __restrict__ x, const int* __restrict__ cidx,
    float* __restrict__ crys, float* __restrict__ cnt){
  int idx = blockIdx.x * 256 + threadIdx.x;
  int n = idx >> 6, f = idx & 63;
  int c = cidx[n];
  atomicAdd(&crys[c * FD + f], x[idx]);
  if (f == 0) atomicAdd(&cnt[c], 1.f);
}

__global__ __launch_bounds__(128) void head_kernel(
    const float* __restrict__ crys, const float* __restrict__ cnt,
    const float* __restrict__ W_fc, const float* __restrict__ b_fc,
    const float* __restrict__ W_out, const float* __restrict__ b_out,
    void* __restrict__ out, const int* __restrict__ flag){
  __shared__ float p_s[FD];
  __shared__ float red_s[HD];
  int c = blockIdx.x, tid = threadIdx.x;
  if (tid < FD){
    float ct = fmaxf(cnt[c], 1.f);
    p_s[tid] = softplusf_(crys[c * FD + tid] / ct);
  }
  __syncthreads();
  float acc = b_fc[tid];
  for (int k = 0; k < FD; k++)
    acc = fmaf(p_s[k], W_fc[k * HD + tid], acc);
  float h = softplusf_(acc);
  red_s[tid] = h * W_out[tid];
  __syncthreads();
  for (int s = HD / 2; s > 0; s >>= 1){
    if (tid < s) red_s[tid] += red_s[tid + s];
    __syncthreads();
  }
  if (tid == 0){
    float r = red_s[0] + b_out[0];
    if (*flag) ((u16*)out)[c] = f2bf(r);
    else       ((float*)out)[c] = r;
  }
}

extern "C" void kernel_launch(void* const* d_in, const int* in_sizes, int n_in,
                              void* d_out, int out_size, void* d_ws, size_t ws_size,
                              hipStream_t stream){
  if (ws_size < WS_NEED_BYTES) return;  // diagnostic: leaves d_out zeroed
  const void* atom_fea = d_in[0];
  const void* nbr_fea  = d_in[1];
  const int* nbr_idx   = (const int*)d_in[2];
  const int* cidx      = (const int*)d_in[3];

  float* ws     = (float*)d_ws;
  float* x      = ws + OFF_X;
  u16*   xh     = (u16*)(ws + OFF_XH);
  float* summed = ws + OFF_SUMMED;
  float* sum1   = ws + OFF_STATS;
  float* sq1    = sum1 + 128;
  float* sum2   = sq1 + 128;
  float* sq2    = sum2 + 64;
  float* crys   = ws + OFF_CRYS;
  float* cnt    = ws + OFF_CNT;
  float* wc     = ws + OFF_WCONV;
  u16*   wbf    = (u16*)(ws + OFF_WBF);
  int*   flag   = (int*)(ws + OFF_FLAG);

  detect_kernel<<<1, 64, 0, stream>>>((const u16*)nbr_fea, flag);
  CvtArgs ca;
  const int srcidx[12] = {4,5,6,7,8,9,10,11,12,13,14,15};
  const int starts[13] = {W_EMB_O, B_EMB_O, W_FULL_O, B_FULL_O, G1_O, BE1_O,
                          G2_O, BE2_O, W_FC_O, B_FC_O, W_OUT_O, B_OUT_O, WC_TOTAL};
  for (int i = 0; i < 12; i++){ ca.src[i] = d_in[srcidx[i]]; ca.start[i] = starts[i]; }
  ca.start[12] = WC_TOTAL;
  cvt_all_kernel<<<(WC_TOTAL + 255) / 256, 256, 0, stream>>>(ca, wc, flag);
  build_bfrag<<<(9216 + 255) / 256, 256, 0, stream>>>(wc + W_FULL_O, wbf);

  embed_kernel<<<NATOM / 4, 256, 0, stream>>>(atom_fea, wc + W_EMB_O, wc + B_EMB_O,
                                              x, xh, flag);
  const int LDS_STATS = 6144 + 2 * 128 * 4;            // 7168
  const int LDS_ACT   = 6144 + (48 * GS + 128) * 4;    // 32000
  for (int i = 0; i < 3; i++){
    const u16* wbf_l = wbf + (size_t)i * 3072 * 8;
    hipMemsetAsync(sum1, 0, 384 * sizeof(float), stream);
    conv_mfma<0><<<3000, 256, LDS_STATS, stream>>>(xh, nbr_fea, nbr_idx, wbf_l,
        wc + B_FULL_O + i * F2D, sum1, sq1, wc + G1_O + i * F2D,
        wc + BE1_O + i * F2D, summed, sum1, sq1, flag);
    conv_mfma<1><<<3000, 256, LDS_ACT, stream>>>(xh, nbr_fea, nbr_idx, wbf_l,
        wc + B_FULL_O + i * F2D, sum1, sq1, wc + G1_O + i * F2D,
        wc + BE1_O + i * F2D, summed, sum2, sq2, flag);
    update_x_kernel<<<(NATOM * FD) / 256, 256, 0, stream>>>(x, xh, summed, sum2, sq2,
        wc + G2_O + i * FD, wc + BE2_O + i * FD);
  }
  hipMemsetAsync(crys, 0, (NCRY * FD + NCRY) * sizeof(float), stream);
  pool_kernel<<<(NATOM * FD) / 256, 256, 0, stream>>>(x, cidx, crys, cnt);
  head_kernel<<<NCRY, 128, 0, stream>>>(crys, cnt, wc + W_FC_O, wc + B_FC_O,
      wc + W_OUT_O, wc + B_OUT_O, d_out, flag);
}

// Round 8
// 1015.057 us; speedup vs baseline: 1.9569x; 1.0841x over previous
//
#include <hip/hip_runtime.h>
#include <hip/hip_bf16.h>

// CGCNN forward, MFMA conv GEMM (R8).
//   g[e,:] = [x[n(e)] | x[nb(e)] | bond(e)] @ Wf + b  (K=169 pad 192, N=128)
// R8 vs R7: bond features are layer-invariant -> one-time repack into
// bond_pad[720000][48] bf16 (96B aligned rows, zero-padded). Conv waves load
// bond A-fragments directly as b128 (no LDS staging, no barrier in stats),
// and all 18 A-fragments are hoisted into one load burst per supertile.
// R7 path kept as runtime fallback if ws_size < 108.5 MB.

#define NATOM 60000
#define MNBR  12
#define F0D   92
#define FBD   41
#define FD    64
#define F2D   128
#define NCRY  2000
#define HD    128
#define NSUP  15000          // 720000 edges / 48
#define GS    132            // gbuf row stride (floats)

// ws layout (float units)
#define OFF_X      0ull          // 3,840,000 f32
#define OFF_XH     3840000ull    // 3,840,000 u16
#define OFF_SUMMED 5760000ull    // 3,840,000 f32
#define OFF_STATS  9600000ull    // sum1[128] sq1[128] sum2[64] sq2[64]
#define OFF_CRYS   9600384ull
#define OFF_CNT    9728384ull
#define OFF_WCONV  9730384ull    // 80,833 f32
#define OFF_WBF    9811220ull    // 73,728 u16 = 36,864 f slots
#define OFF_FLAG   9848084ull
#define WS_NEED_BYTES (9848085ull * 4ull)
#define OFF_BPAD   9848088ull    // 34,560,000 u16 = 17,280,000 f slots (16B aligned)
#define WS_FULL_BYTES ((OFF_BPAD + 17280000ull) * 4ull)   // 108,512,352

// offsets inside wconv
#define W_EMB_O  0
#define B_EMB_O  5888
#define W_FULL_O 5952
#define B_FULL_O 70848
#define G1_O     71232
#define BE1_O    71616
#define G2_O     72000
#define BE2_O    72192
#define W_FC_O   72384
#define B_FC_O   80576
#define W_OUT_O  80704
#define B_OUT_O  80832
#define WC_TOTAL 80833

typedef unsigned short u16;
typedef __attribute__((ext_vector_type(8))) short bf16x8;
typedef __attribute__((ext_vector_type(4))) float f32x4;

__device__ __forceinline__ float bf2f(u16 u){
  union { unsigned int i; float f; } v; v.i = ((unsigned int)u) << 16; return v.f;
}
__device__ __forceinline__ u16 f2bf(float f){
  union { float f; unsigned int i; } v; v.f = f;
  unsigned int x = v.i;
  return (u16)((x + 0x7FFFu + ((x >> 16) & 1u)) >> 16);
}
__device__ __forceinline__ float softplusf_(float x){
  return fmaxf(x, 0.f) + log1pf(expf(-fabsf(x)));
}
__device__ __forceinline__ float softplus_fast(float x){
  return fmaxf(x, 0.f) + __logf(1.f + __expf(-fabsf(x)));
}
__device__ __forceinline__ float sigmoid_fast(float x){
  return __builtin_amdgcn_rcpf(1.f + __expf(-x));
}

__global__ __launch_bounds__(64) void detect_kernel(
    const u16* __restrict__ data, int* __restrict__ flag){
  int tid = threadIdx.x;
  float v = bf2f(data[tid * 2]);
  float av = fabsf(v);
  bool sane = (av > 1e-6f) && (av < 100.f);
  unsigned long long m = __ballot(sane);
  if (tid == 0) *flag = (__popcll(m) >= 32) ? 1 : 0;
}

struct CvtArgs {
  const void* src[12];
  int start[13];
};

__global__ __launch_bounds__(256) void cvt_all_kernel(
    CvtArgs a, float* __restrict__ dst, const int* __restrict__ flag){
  int i = blockIdx.x * 256 + threadIdx.x;
  if (i >= WC_TOTAL) return;
  int r = 0;
  while (i >= a.start[r + 1]) r++;
  int rel = i - a.start[r];
  if (*flag) dst[i] = bf2f(((const u16*)a.src[r])[rel]);
  else       dst[i] = ((const float*)a.src[r])[rel];
}

__global__ __launch_bounds__(256) void build_bfrag(
    const float* __restrict__ wfull, u16* __restrict__ wbf){
  int t = blockIdx.x * 256 + threadIdx.x;
  if (t >= 3 * 6 * 8 * 64) return;
  int lane = t & 63, nt = (t >> 6) & 7, c = (t >> 9) % 6, layer = t / 3072;
  int q = lane >> 4, nloc = lane & 15;
  u16 vals[8];
  #pragma unroll
  for (int i = 0; i < 8; i++){
    int k = c * 32 + q * 8 + i;
    float v = (k < 169) ? wfull[layer * 169 * F2D + k * F2D + nt * 16 + nloc] : 0.f;
    vals[i] = f2bf(v);
  }
  *(uint4*)&wbf[(size_t)t * 8] = *(uint4*)vals;
}

// One-time repack: bond_pad[e][0..47] = bf16(nbr_fea[e][k]) (0 for k>=41).
// Block per supertile: coalesced uint4 stage to LDS, scatter-pad out.
__global__ __launch_bounds__(256) void bond_prep(
    const void* __restrict__ nbr_fea, u16* __restrict__ bond_pad,
    const int* __restrict__ flag){
  __shared__ __align__(16) char sm[7872];
  u16*   lb_u = (u16*)sm;
  float* lb_f = (float*)sm;
  int s = blockIdx.x, tid = threadIdx.x;
  const int isbf = *flag;
  if (isbf){
    const uint4* src = (const uint4*)((const u16*)nbr_fea + (size_t)s * 1968);
    if (tid < 246) ((uint4*)sm)[tid] = src[tid];
  } else {
    const uint4* src = (const uint4*)((const float*)nbr_fea + (size_t)s * 1968);
    for (int t = tid; t < 492; t += 256) ((uint4*)sm)[t] = src[t];
  }
  __syncthreads();
  uint4* outv = (uint4*)(bond_pad + (size_t)s * 2304);
  for (int slot = tid; slot < 288; slot += 256){
    int el = slot / 6, jj = slot - el * 6;
    u16 v[8];
    #pragma unroll
    for (int i = 0; i < 8; i++){
      int k = jj * 8 + i;
      v[i] = (k < FBD) ? (isbf ? lb_u[el * FBD + k] : f2bf(lb_f[el * FBD + k])) : (u16)0;
    }
    outv[slot] = *(uint4*)v;
  }
}

__global__ __launch_bounds__(256) void embed_kernel(
    const void* __restrict__ atom_fea, const float* __restrict__ W_emb,
    const float* __restrict__ b_emb, float* __restrict__ x,
    u16* __restrict__ xh, const int* __restrict__ flag){
  int tid = threadIdx.x;
  int n = blockIdx.x * 4 + (tid >> 6);
  int f = tid & 63;
  float acc = b_emb[f];
  if (*flag){
    const u16* arow = (const u16*)atom_fea + n * F0D;
    for (int k = 0; k < F0D; k++)
      acc = fmaf(bf2f(arow[k]), W_emb[k * FD + f], acc);
  } else {
    const float* arow = (const float*)atom_fea + n * F0D;
    for (int k = 0; k < F0D; k++)
      acc = fmaf(arow[k], W_emb[k * FD + f], acc);
  }
  x[n * FD + f] = acc;
  xh[n * FD + f] = f2bf(acc);
}

// MFMA conv pass. ACT: 0 = BN1 stats only, 1 = fused act+sum+BN2 stats.
// PAD: 1 = bond_pad direct b128 loads (no staging); 0 = R7 LDS-build fallback.
template<int ACT, int PAD>
__global__ __launch_bounds__(256, 3) void conv_mfma(
    const u16* __restrict__ xh, const void* __restrict__ nbr_fea,
    const u16* __restrict__ bond_pad,
    const int* __restrict__ nbr_idx, const u16* __restrict__ wbf_l,
    const float* __restrict__ bfull, const float* __restrict__ sum1,
    const float* __restrict__ sq1, const float* __restrict__ g1,
    const float* __restrict__ be1, float* __restrict__ summed,
    float* __restrict__ o_sum, float* __restrict__ o_sq,
    const int* __restrict__ flag){
  extern __shared__ char smem[];
  u16*   fragA = (u16*)smem;                      // PAD=0 only: 6*512 u16
  const int base_off = PAD ? 0 : 6144;
  float* gbuf  = (float*)(smem + base_off);       // ACT only: 48*GS
  float* redS  = ACT ? (gbuf + 48 * GS) : (float*)(smem + base_off);
  float* redQ  = redS + (ACT ? 64 : 128);

  const int tid = threadIdx.x;
  const int w = tid >> 6, lane = tid & 63;
  const int q = lane >> 4, nloc = lane & 15, q8 = q * 8;
  const int isbf = *flag;

  bf16x8 Bf[6][2];
  const bf16x8* Bv = (const bf16x8*)wbf_l;
  #pragma unroll
  for (int c = 0; c < 6; c++)
    #pragma unroll
    for (int t2 = 0; t2 < 2; t2++)
      Bf[c][t2] = Bv[(c * 8 + w * 2 + t2) * 64 + lane];
  float bias0 = bfull[w * 32 + nloc];
  float bias1 = bfull[w * 32 + 16 + nloc];

  float A0 = 0.f, B0 = 0.f, A1 = 0.f, B1 = 0.f;
  if (ACT){
    const float invR = 1.f / (float)(NATOM * MNBR);
    float m0 = sum1[lane] * invR;
    float v0 = fmaxf(sq1[lane] * invR - m0 * m0, 0.f);
    A0 = g1[lane] * rsqrtf(v0 + 1e-5f);  B0 = be1[lane] - m0 * A0;
    float m1 = sum1[64 + lane] * invR;
    float v1 = fmaxf(sq1[64 + lane] * invR - m1 * m1, 0.f);
    A1 = g1[64 + lane] * rsqrtf(v1 + 1e-5f);  B1 = be1[64 + lane] - m1 * A1;
  }
  float sAcc0 = 0.f, sAcc1 = 0.f, qAcc0 = 0.f, qAcc1 = 0.f;
  if (tid < (ACT ? 64 : 128)){ redS[tid] = 0.f; redQ[tid] = 0.f; }
  if (PAD && !ACT) ; // no barrier needed until the end (init/use ordering via final sync)

  const bf16x8* xv = (const bf16x8*)xh;
  const bf16x8 zero8 = {0,0,0,0,0,0,0,0};
  for (int s = blockIdx.x; s < NSUP; s += gridDim.x){
    int e0 = s * 48 + nloc;
    int nb0 = nbr_idx[e0], nb1 = nbr_idx[e0 + 16], nb2 = nbr_idx[e0 + 32];
    bf16x8 Af[3][6];
    if (PAD){
      #pragma unroll
      for (int et = 0; et < 3; et++){
        int nb = (et == 0) ? nb0 : (et == 1) ? nb1 : nb2;
        int na = s * 4 + (et * 16 + nloc) / 12;
        Af[et][0] = xv[na * 8 + q];
        Af[et][1] = xv[na * 8 + 4 + q];
        Af[et][2] = xv[nb * 8 + q];
        Af[et][3] = xv[nb * 8 + 4 + q];
        const bf16x8* bpv = (const bf16x8*)(bond_pad + (size_t)(e0 + et * 16) * 48);
        Af[et][4] = bpv[q];
        Af[et][5] = (q < 2) ? bpv[4 + q] : zero8;
      }
    } else {
      if (w < 3){
        size_t eg = (size_t)(s * 48 + w * 16 + nloc);
        u16 v4[8], v5[8];
        if (isbf){
          const u16* br = (const u16*)nbr_fea + eg * 41;
          #pragma unroll
          for (int i = 0; i < 8; i++) v4[i] = br[q8 + i];
          #pragma unroll
          for (int i = 0; i < 8; i++){
            int k5 = 32 + q8 + i;
            v5[i] = (k5 < 41) ? br[k5] : (u16)0;
          }
        } else {
          const float* br = (const float*)nbr_fea + eg * 41;
          #pragma unroll
          for (int i = 0; i < 8; i++) v4[i] = f2bf(br[q8 + i]);
          #pragma unroll
          for (int i = 0; i < 8; i++){
            int k5 = 32 + q8 + i;
            v5[i] = (k5 < 41) ? f2bf(br[k5]) : (u16)0;
          }
        }
        *(uint4*)&fragA[(w * 2 + 0) * 512 + lane * 8] = *(uint4*)v4;
        *(uint4*)&fragA[(w * 2 + 1) * 512 + lane * 8] = *(uint4*)v5;
      }
      __syncthreads();
      #pragma unroll
      for (int et = 0; et < 3; et++){
        int nb = (et == 0) ? nb0 : (et == 1) ? nb1 : nb2;
        int na = s * 4 + (et * 16 + nloc) / 12;
        Af[et][0] = xv[na * 8 + q];
        Af[et][1] = xv[na * 8 + 4 + q];
        Af[et][2] = xv[nb * 8 + q];
        Af[et][3] = xv[nb * 8 + 4 + q];
        Af[et][4] = *(bf16x8*)&fragA[(et * 2 + 0) * 512 + lane * 8];
        Af[et][5] = *(bf16x8*)&fragA[(et * 2 + 1) * 512 + lane * 8];
      }
    }
    #pragma unroll
    for (int et = 0; et < 3; et++){
      #pragma unroll
      for (int t2 = 0; t2 < 2; t2++){
        float bs = t2 ? bias1 : bias0;
        f32x4 acc = {bs, bs, bs, bs};
        acc = __builtin_amdgcn_mfma_f32_16x16x32_bf16(Af[et][0], Bf[0][t2], acc, 0, 0, 0);
        acc = __builtin_amdgcn_mfma_f32_16x16x32_bf16(Af[et][1], Bf[1][t2], acc, 0, 0, 0);
        acc = __builtin_amdgcn_mfma_f32_16x16x32_bf16(Af[et][2], Bf[2][t2], acc, 0, 0, 0);
        acc = __builtin_amdgcn_mfma_f32_16x16x32_bf16(Af[et][3], Bf[3][t2], acc, 0, 0, 0);
        acc = __builtin_amdgcn_mfma_f32_16x16x32_bf16(Af[et][4], Bf[4][t2], acc, 0, 0, 0);
        acc = __builtin_amdgcn_mfma_f32_16x16x32_bf16(Af[et][5], Bf[5][t2], acc, 0, 0, 0);
        if (ACT){
          int col = w * 32 + t2 * 16 + nloc;
          int r0 = et * 16 + q * 4;
          gbuf[(r0 + 0) * GS + col] = acc[0];
          gbuf[(r0 + 1) * GS + col] = acc[1];
          gbuf[(r0 + 2) * GS + col] = acc[2];
          gbuf[(r0 + 3) * GS + col] = acc[3];
        } else {
          float ss = acc[0] + acc[1] + acc[2] + acc[3];
          float qq = acc[0]*acc[0] + acc[1]*acc[1] + acc[2]*acc[2] + acc[3]*acc[3];
          if (t2){ sAcc1 += ss; qAcc1 += qq; } else { sAcc0 += ss; qAcc0 += qq; }
        }
      }
    }
    if (ACT){
      __syncthreads();   // g complete
      float p = 0.f;
      #pragma unroll
      for (int m = 0; m < 12; m++){
        int el = w * 12 + m;
        float u = fmaf(gbuf[el * GS + lane],      A0, B0);
        float v = fmaf(gbuf[el * GS + 64 + lane], A1, B1);
        p = fmaf(sigmoid_fast(u), softplus_fast(v), p);
      }
      summed[(s * 4 + w) * 64 + lane] = p;
      sAcc0 += p;  qAcc0 = fmaf(p, p, qAcc0);
      __syncthreads();   // protect gbuf for next iteration
    } else if (!PAD){
      __syncthreads();   // protect fragA
    }
  }
  __syncthreads();
  if (ACT){
    atomicAdd(&redS[lane], sAcc0);
    atomicAdd(&redQ[lane], qAcc0);
    __syncthreads();
    if (tid < 64){ atomicAdd(&o_sum[tid], redS[tid]); atomicAdd(&o_sq[tid], redQ[tid]); }
  } else {
    int c0 = w * 32 + nloc;
    atomicAdd(&redS[c0], sAcc0);       atomicAdd(&redQ[c0], qAcc0);
    atomicAdd(&redS[c0 + 16], sAcc1);  atomicAdd(&redQ[c0 + 16], qAcc1);
    __syncthreads();
    if (tid < 128){ atomicAdd(&o_sum[tid], redS[tid]); atomicAdd(&o_sq[tid], redQ[tid]); }
  }
}

__global__ __launch_bounds__(256) void update_x_kernel(
    float* __restrict__ x, u16* __restrict__ xh,
    const float* __restrict__ summed,
    const float* __restrict__ sum2, const float* __restrict__ sq2,
    const float* __restrict__ g2, const float* __restrict__ be2){
  int idx = blockIdx.x * 256 + threadIdx.x;
  int f = idx & 63;
  const float invN = 1.f / (float)NATOM;
  float mean = sum2[f] * invN;
  float var  = fmaxf(sq2[f] * invN - mean * mean, 0.f);
  float a = g2[f] * rsqrtf(var + 1e-5f);
  float b = be2[f] - mean * a;
  float v = x[idx] + fmaf(summed[idx], a, b);
  float r = softplusf_(v);
  x[idx] = r;
  xh[idx] = f2bf(r);
}

__global__ __launch_bounds__(256) void pool_kernel(
    const float* __restrict__ x, const int* __restrict__ cidx,
    float* __restrict__ crys, float* __restrict__ cnt){
  int idx = blockIdx.x * 256 + threadIdx.x;
  int n = idx >> 6, f = idx & 63;
  int c = cidx[n];
  atomicAdd(&crys[c * FD + f], x[idx]);
  if (f == 0) atomicAdd(&cnt[c], 1.f);
}

__global__ __launch_bounds__(128) void head_kernel(
    const float* __restrict__ crys, const float* __restrict__ cnt,
    const float* __restrict__ W_fc, const float* __restrict__ b_fc,
    const float* __restrict__ W_out, const float* __restrict__ b_out,
    void* __restrict__ out, const int* __restrict__ flag){
  __shared__ float p_s[FD];
  __shared__ float red_s[HD];
  int c = blockIdx.x, tid = threadIdx.x;
  if (tid < FD){
    float ct = fmaxf(cnt[c], 1.f);
    p_s[tid] = softplusf_(crys[c * FD + tid] / ct);
  }
  __syncthreads();
  float acc = b_fc[tid];
  for (int k = 0; k < FD; k++)
    acc = fmaf(p_s[k], W_fc[k * HD + tid], acc);
  float h = softplusf_(acc);
  red_s[tid] = h * W_out[tid];
  __syncthreads();
  for (int s = HD / 2; s > 0; s >>= 1){
    if (tid < s) red_s[tid] += red_s[tid + s];
    __syncthreads();
  }
  if (tid == 0){
    float r = red_s[0] + b_out[0];
    if (*flag) ((u16*)out)[c] = f2bf(r);
    else       ((float*)out)[c] = r;
  }
}

extern "C" void kernel_launch(void* const* d_in, const int* in_sizes, int n_in,
                              void* d_out, int out_size, void* d_ws, size_t ws_size,
                              hipStream_t stream){
  if (ws_size < WS_NEED_BYTES) return;  // diagnostic: leaves d_out zeroed
  const bool full = (ws_size >= WS_FULL_BYTES);
  const void* atom_fea = d_in[0];
  const void* nbr_fea  = d_in[1];
  const int* nbr_idx   = (const int*)d_in[2];
  const int* cidx      = (const int*)d_in[3];

  float* ws     = (float*)d_ws;
  float* x      = ws + OFF_X;
  u16*   xh     = (u16*)(ws + OFF_XH);
  float* summed = ws + OFF_SUMMED;
  float* sum1   = ws + OFF_STATS;
  float* sq1    = sum1 + 128;
  float* sum2   = sq1 + 128;
  float* sq2    = sum2 + 64;
  float* crys   = ws + OFF_CRYS;
  float* cnt    = ws + OFF_CNT;
  float* wc     = ws + OFF_WCONV;
  u16*   wbf    = (u16*)(ws + OFF_WBF);
  int*   flag   = (int*)(ws + OFF_FLAG);
  u16*   bpad   = (u16*)(ws + OFF_BPAD);

  detect_kernel<<<1, 64, 0, stream>>>((const u16*)nbr_fea, flag);
  CvtArgs ca;
  const int srcidx[12] = {4,5,6,7,8,9,10,11,12,13,14,15};
  const int starts[13] = {W_EMB_O, B_EMB_O, W_FULL_O, B_FULL_O, G1_O, BE1_O,
                          G2_O, BE2_O, W_FC_O, B_FC_O, W_OUT_O, B_OUT_O, WC_TOTAL};
  for (int i = 0; i < 12; i++){ ca.src[i] = d_in[srcidx[i]]; ca.start[i] = starts[i]; }
  ca.start[12] = WC_TOTAL;
  cvt_all_kernel<<<(WC_TOTAL + 255) / 256, 256, 0, stream>>>(ca, wc, flag);
  build_bfrag<<<(9216 + 255) / 256, 256, 0, stream>>>(wc + W_FULL_O, wbf);
  if (full) bond_prep<<<NSUP, 256, 0, stream>>>(nbr_fea, bpad, flag);

  embed_kernel<<<NATOM / 4, 256, 0, stream>>>(atom_fea, wc + W_EMB_O, wc + B_EMB_O,
                                              x, xh, flag);
  const int LDS_STATS_P = 2 * 128 * 4;                   // 1024
  const int LDS_ACT_P   = (48 * GS + 128) * 4;           // 25856
  const int LDS_STATS_F = 6144 + 2 * 128 * 4;            // 7168
  const int LDS_ACT_F   = 6144 + (48 * GS + 128) * 4;    // 32000
  for (int i = 0; i < 3; i++){
    const u16* wbf_l = wbf + (size_t)i * 3072 * 8;
    hipMemsetAsync(sum1, 0, 384 * sizeof(float), stream);
    if (full){
      conv_mfma<0,1><<<3000, 256, LDS_STATS_P, stream>>>(xh, nbr_fea, bpad, nbr_idx,
          wbf_l, wc + B_FULL_O + i * F2D, sum1, sq1, wc + G1_O + i * F2D,
          wc + BE1_O + i * F2D, summed, sum1, sq1, flag);
      conv_mfma<1,1><<<3000, 256, LDS_ACT_P, stream>>>(xh, nbr_fea, bpad, nbr_idx,
          wbf_l, wc + B_FULL_O + i * F2D, sum1, sq1, wc + G1_O + i * F2D,
          wc + BE1_O + i * F2D, summed, sum2, sq2, flag);
    } else {
      conv_mfma<0,0><<<3000, 256, LDS_STATS_F, stream>>>(xh, nbr_fea, bpad, nbr_idx,
          wbf_l, wc + B_FULL_O + i * F2D, sum1, sq1, wc + G1_O + i * F2D,
          wc + BE1_O + i * F2D, summed, sum1, sq1, flag);
      conv_mfma<1,0><<<3000, 256, LDS_ACT_F, stream>>>(xh, nbr_fea, bpad, nbr_idx,
          wbf_l, wc + B_FULL_O + i * F2D, sum1, sq1, wc + G1_O + i * F2D,
          wc + BE1_O + i * F2D, summed, sum2, sq2, flag);
    }
    update_x_kernel<<<(NATOM * FD) / 256, 256, 0, stream>>>(x, xh, summed, sum2, sq2,
        wc + G2_O + i * FD, wc + BE2_O + i * FD);
  }
  hipMemsetAsync(crys, 0, (NCRY * FD + NCRY) * sizeof(float), stream);
  pool_kernel<<<(NATOM * FD) / 256, 256, 0, stream>>>(x, cidx, crys, cnt);
  head_kernel<<<NCRY, 128, 0, stream>>>(crys, cnt, wc + W_FC_O, wc + B_FC_O,
      wc + W_OUT_O, wc + B_OUT_O, d_out, flag);
}